// Round 1
// baseline (1473.783 us; speedup 1.0000x reference)
//
#include <hip/hip_runtime.h>
#include <cstdint>
#include <cstddef>
#include <math.h>

#define NN 100000
#define NE 1600000

// ---------- index-width detection (int64 vs int32 edge_index) ----------
// For int64 data with values < 2^31, every odd 32-bit word is 0.
// For int32 data, odd words are random node ids (nonzero w.h.p.).
__global__ __launch_bounds__(64) void k_detect(const int* __restrict__ p, int* flag) {
    int nz = 0;
    for (int i = threadIdx.x; i < 1024; i += 64) nz |= (p[2 * i + 1] != 0);
    unsigned long long b = __ballot(nz != 0);
    if (threadIdx.x == 0) *flag = (b == 0ULL) ? 1 : 0;  // 1 => int64
}

__device__ __forceinline__ int load_idx(const void* ei, int isI64, int pos) {
    if (isI64) return (int)((const long long*)ei)[pos];
    return ((const int*)ei)[pos];
}

// ---------- degree / norm ----------
__global__ __launch_bounds__(256) void k_deg_init(int* deg) {
    int i = blockIdx.x * 256 + threadIdx.x;
    if (i < NN) deg[i] = 1;  // self-loop
}

__global__ __launch_bounds__(256) void k_deg_count(const void* __restrict__ ei,
                                                   const int* __restrict__ flag, int* deg) {
    int e = blockIdx.x * 256 + threadIdx.x;
    if (e < NE) {
        int isI64 = *flag;
        atomicAdd(&deg[load_idx(ei, isI64, NE + e)], 1);
    }
}

__global__ __launch_bounds__(256) void k_dis(const int* __restrict__ deg, float* dis) {
    int i = blockIdx.x * 256 + threadIdx.x;
    if (i < NN) dis[i] = rsqrtf((float)deg[i]);
}

// ---------- dense GEMM: one wave per node, lane = output feature ----------
template <int K, int F, bool RELU>
__global__ __launch_bounds__(256) void k_gemm(const float* __restrict__ x,
                                              const float* __restrict__ W,
                                              float* __restrict__ out) {
    __shared__ float Wl[K * F];
    for (int i = threadIdx.x; i < K * F; i += 256) Wl[i] = W[i];
    __syncthreads();
    int node = blockIdx.x * 4 + (threadIdx.x >> 6);
    int j = threadIdx.x & 63;
    if (node >= NN || j >= F) return;
    const float* xr = x + (size_t)node * K;
    float acc = 0.f;
#pragma unroll
    for (int k = 0; k < K; k += 4) {
        float4 xv = *(const float4*)(xr + k);
        if (RELU) {
            xv.x = fmaxf(xv.x, 0.f); xv.y = fmaxf(xv.y, 0.f);
            xv.z = fmaxf(xv.z, 0.f); xv.w = fmaxf(xv.w, 0.f);
        }
        acc = fmaf(xv.x, Wl[(k + 0) * F + j], acc);
        acc = fmaf(xv.y, Wl[(k + 1) * F + j], acc);
        acc = fmaf(xv.z, Wl[(k + 2) * F + j], acc);
        acc = fmaf(xv.w, Wl[(k + 3) * F + j], acc);
    }
    out[(size_t)node * F + j] = acc;
}

// ---------- self-loop + bias init: out[n][f] = h[n][f]*dis[n]^2 + b[f] ----------
template <int F>
__global__ __launch_bounds__(256) void k_selfinit(const float* __restrict__ h,
                                                  const float* __restrict__ dis,
                                                  const float* __restrict__ b,
                                                  float* __restrict__ out) {
    long long i = (long long)blockIdx.x * 256 + threadIdx.x;
    if (i < (long long)NN * F) {
        int n = (int)(i / F);
        int f = (int)(i - (long long)n * F);
        float dv = dis[n];
        out[i] = h[i] * dv * dv + b[f];
    }
}

// ---------- edge aggregation (atomic scatter): one wave per edge ----------
template <int F>
__global__ __launch_bounds__(256) void k_agg(const void* __restrict__ ei,
                                             const int* __restrict__ flag,
                                             const float* __restrict__ dis,
                                             const float* __restrict__ h,
                                             float* out) {
    int w = (blockIdx.x * 256 + threadIdx.x) >> 6;
    int f = threadIdx.x & 63;
    if (w >= NE) return;
    int isI64 = *flag;
    int s = load_idx(ei, isI64, w);
    int d = load_idx(ei, isI64, NE + w);
    float nrm = dis[s] * dis[d];
    if (f < F) atomicAdd(&out[(size_t)d * F + f], h[(size_t)s * F + f] * nrm);
}

// ---------- log_softmax over 40 classes: one wave per node ----------
__global__ __launch_bounds__(256) void k_logsoftmax(float* __restrict__ out) {
    int n = (blockIdx.x * 256 + threadIdx.x) >> 6;
    int f = threadIdx.x & 63;
    if (n >= NN) return;
    float v = (f < 40) ? out[(size_t)n * 40 + f] : -INFINITY;
    float m = v;
#pragma unroll
    for (int off = 32; off; off >>= 1) m = fmaxf(m, __shfl_xor(m, off));
    float ex = (f < 40) ? __expf(v - m) : 0.f;
    float sum = ex;
#pragma unroll
    for (int off = 32; off; off >>= 1) sum += __shfl_xor(sum, off);
    if (f < 40) out[(size_t)n * 40 + f] = v - m - logf(sum);
}

extern "C" void kernel_launch(void* const* d_in, const int* in_sizes, int n_in,
                              void* d_out, int out_size, void* d_ws, size_t ws_size,
                              hipStream_t stream) {
    const float* x  = (const float*)d_in[0];
    const void*  ei = d_in[1];
    const float* W1 = (const float*)d_in[2];
    const float* b1 = (const float*)d_in[3];
    const float* W2 = (const float*)d_in[4];
    const float* b2 = (const float*)d_in[5];
    const float* W3 = (const float*)d_in[6];
    const float* b3 = (const float*)d_in[7];
    float* out = (float*)d_out;

    char* ws = (char*)d_ws;
    int*   deg  = (int*)ws;                          // 400 KB
    float* dis  = (float*)(ws + 400000);             // 400 KB
    float* bufA = (float*)(ws + 800000);             // 25.6 MB
    float* bufB = (float*)(ws + 800000 + 25600000);  // 25.6 MB
    int*   flag = (int*)(ws + 800000 + 2 * 25600000);

    k_detect<<<1, 64, 0, stream>>>((const int*)ei, flag);
    k_deg_init<<<(NN + 255) / 256, 256, 0, stream>>>(deg);
    k_deg_count<<<(NE + 255) / 256, 256, 0, stream>>>(ei, flag, deg);
    k_dis<<<(NN + 255) / 256, 256, 0, stream>>>(deg, dis);

    const int gemm_grid = (NN + 3) / 4;
    const int agg_grid  = (int)(((long long)NE * 64 + 255) / 256);

    // layer 1: h1 = relu(Agg(x@W1) + b1)   (relu fused into next gemm's load)
    k_gemm<128, 64, false><<<gemm_grid, 256, 0, stream>>>(x, W1, bufA);
    k_selfinit<64><<<(NN * 64 + 255) / 256, 256, 0, stream>>>(bufA, dis, b1, bufB);
    k_agg<64><<<agg_grid, 256, 0, stream>>>(ei, flag, dis, bufA, bufB);

    // layer 2
    k_gemm<64, 64, true><<<gemm_grid, 256, 0, stream>>>(bufB, W2, bufA);
    k_selfinit<64><<<(NN * 64 + 255) / 256, 256, 0, stream>>>(bufA, dis, b2, bufB);
    k_agg<64><<<agg_grid, 256, 0, stream>>>(ei, flag, dis, bufA, bufB);

    // layer 3: aggregate straight into d_out, then in-place log_softmax
    k_gemm<64, 40, true><<<gemm_grid, 256, 0, stream>>>(bufB, W3, bufA);
    k_selfinit<40><<<(NN * 40 + 255) / 256, 256, 0, stream>>>(bufA, dis, b3, out);
    k_agg<40><<<agg_grid, 256, 0, stream>>>(ei, flag, dis, bufA, out);

    k_logsoftmax<<<(NN + 3) / 4, 256, 0, stream>>>(out);
}

// Round 2
// 834.129 us; speedup vs baseline: 1.7669x; 1.7669x over previous
//
#include <hip/hip_runtime.h>
#include <cstdint>
#include <cstddef>
#include <math.h>

#define NN 100000
#define NE 1600000
#define SCAN_BLOCKS ((NN + 255) / 256)   // 391

// ---------- index-width detection (int64 vs int32 edge_index) ----------
__global__ __launch_bounds__(64) void k_detect(const int* __restrict__ p, int* flag) {
    int nz = 0;
    for (int i = threadIdx.x; i < 1024; i += 64) nz |= (p[2 * i + 1] != 0);
    unsigned long long b = __ballot(nz != 0);
    if (threadIdx.x == 0) *flag = (b == 0ULL) ? 1 : 0;  // 1 => int64
}

__device__ __forceinline__ int load_idx(const void* ei, int isI64, int pos) {
    if (isI64) return (int)((const long long*)ei)[pos];
    return ((const int*)ei)[pos];
}

// ---------- degree / norm ----------
__global__ __launch_bounds__(256) void k_deg_init(int* deg) {
    int i = blockIdx.x * 256 + threadIdx.x;
    if (i < NN) deg[i] = 0;  // in-edges only; self-loop handled analytically
}

__global__ __launch_bounds__(256) void k_deg_count(const void* __restrict__ ei,
                                                   const int* __restrict__ flag, int* deg) {
    int e = blockIdx.x * 256 + threadIdx.x;
    if (e < NE) {
        int isI64 = *flag;
        atomicAdd(&deg[load_idx(ei, isI64, NE + e)], 1);
    }
}

__global__ __launch_bounds__(256) void k_dis(const int* __restrict__ deg, float* dis) {
    int i = blockIdx.x * 256 + threadIdx.x;
    if (i < NN) dis[i] = rsqrtf((float)(deg[i] + 1));  // +1 self-loop
}

// ---------- exclusive scan of deg -> offs (3-phase) ----------
__global__ __launch_bounds__(256) void k_scan1(const int* __restrict__ deg,
                                               int* __restrict__ offs, int* __restrict__ bsum) {
    __shared__ int tmp[256];
    int i = blockIdx.x * 256 + threadIdx.x;
    int v = (i < NN) ? deg[i] : 0;
    tmp[threadIdx.x] = v;
    __syncthreads();
#pragma unroll
    for (int off = 1; off < 256; off <<= 1) {
        int t = (threadIdx.x >= off) ? tmp[threadIdx.x - off] : 0;
        __syncthreads();
        tmp[threadIdx.x] += t;
        __syncthreads();
    }
    if (i < NN) offs[i] = tmp[threadIdx.x] - v;  // exclusive within block
    if (threadIdx.x == 255) bsum[blockIdx.x] = tmp[255];
}

__global__ __launch_bounds__(512) void k_scan2(int* __restrict__ bsum) {
    __shared__ int tmp[512];
    int v = (threadIdx.x < SCAN_BLOCKS) ? bsum[threadIdx.x] : 0;
    tmp[threadIdx.x] = v;
    __syncthreads();
#pragma unroll
    for (int off = 1; off < 512; off <<= 1) {
        int t = (threadIdx.x >= off) ? tmp[threadIdx.x - off] : 0;
        __syncthreads();
        tmp[threadIdx.x] += t;
        __syncthreads();
    }
    if (threadIdx.x < SCAN_BLOCKS) bsum[threadIdx.x] = tmp[threadIdx.x] - v;  // exclusive
}

__global__ __launch_bounds__(256) void k_scan3(int* __restrict__ offs,
                                               const int* __restrict__ bsum,
                                               int* __restrict__ cursor) {
    int i = blockIdx.x * 256 + threadIdx.x;
    if (i < NN) {
        int o = offs[i] + bsum[blockIdx.x];
        offs[i] = o;
        cursor[i] = o;
    }
}

// ---------- CSR placement: csr[slot] = {src, dis[src]} ----------
__global__ __launch_bounds__(256) void k_place(const void* __restrict__ ei,
                                               const int* __restrict__ flag,
                                               const float* __restrict__ dis,
                                               int* cursor, int2* __restrict__ csr) {
    int e = blockIdx.x * 256 + threadIdx.x;
    if (e >= NE) return;
    int isI64 = *flag;
    int s = load_idx(ei, isI64, e);
    int d = load_idx(ei, isI64, NE + e);
    int slot = atomicAdd(&cursor[d], 1);
    int2 pk;
    pk.x = s;
    pk.y = __float_as_int(dis[s]);
    csr[slot] = pk;
}

// ---------- dense GEMM: one wave per node, lane = output feature ----------
template <int K, int F, bool RELU>
__global__ __launch_bounds__(256) void k_gemm(const float* __restrict__ x,
                                              const float* __restrict__ W,
                                              float* __restrict__ out) {
    __shared__ float Wl[K * F];
    for (int i = threadIdx.x; i < K * F; i += 256) Wl[i] = W[i];
    __syncthreads();
    int node = blockIdx.x * 4 + (threadIdx.x >> 6);
    int j = threadIdx.x & 63;
    if (node >= NN || j >= F) return;
    const float* xr = x + (size_t)node * K;
    float acc = 0.f;
#pragma unroll
    for (int k = 0; k < K; k += 4) {
        float4 xv = *(const float4*)(xr + k);
        if (RELU) {
            xv.x = fmaxf(xv.x, 0.f); xv.y = fmaxf(xv.y, 0.f);
            xv.z = fmaxf(xv.z, 0.f); xv.w = fmaxf(xv.w, 0.f);
        }
        acc = fmaf(xv.x, Wl[(k + 0) * F + j], acc);
        acc = fmaf(xv.y, Wl[(k + 1) * F + j], acc);
        acc = fmaf(xv.z, Wl[(k + 2) * F + j], acc);
        acc = fmaf(xv.w, Wl[(k + 3) * F + j], acc);
    }
    out[(size_t)node * F + j] = acc;
}

// ---------- gather aggregation: one wave per node ----------
// out[n][f] = dis[n] * ( sum_e dis[src_e]*h[src_e][f] + dis[n]*h[n][f] ) + b[f]
template <int F, bool SOFTMAX>
__global__ __launch_bounds__(256) void k_gather(const int* __restrict__ offs,
                                                const int* __restrict__ deg,
                                                const int2* __restrict__ csr,
                                                const float* __restrict__ dis,
                                                const float* __restrict__ h,
                                                const float* __restrict__ b,
                                                float* __restrict__ out) {
    int n = blockIdx.x * 4 + (threadIdx.x >> 6);
    int f = threadIdx.x & 63;
    if (n >= NN) return;
    int fc = (f < F) ? f : 0;  // clamp so inactive lanes read valid addrs
    float dv = dis[n];
    float acc = dv * h[(size_t)n * F + fc];  // self-loop term
    int start = offs[n];
    int len = deg[n];
    int i = 0;
    for (; i + 1 < len; i += 2) {
        int2 p0 = csr[start + i];
        int2 p1 = csr[start + i + 1];
        float h0 = h[(size_t)p0.x * F + fc];
        float h1 = h[(size_t)p1.x * F + fc];
        acc = fmaf(__int_as_float(p0.y), h0, acc);
        acc = fmaf(__int_as_float(p1.y), h1, acc);
    }
    if (i < len) {
        int2 p0 = csr[start + i];
        acc = fmaf(__int_as_float(p0.y), h[(size_t)p0.x * F + fc], acc);
    }
    float v = dv * acc + b[fc];
    if (!SOFTMAX) {
        if (f < F) out[(size_t)n * F + f] = v;
    } else {
        float vv = (f < F) ? v : -INFINITY;
        float m = vv;
#pragma unroll
        for (int off = 32; off; off >>= 1) m = fmaxf(m, __shfl_xor(m, off));
        float ex = (f < F) ? __expf(vv - m) : 0.f;
        float sum = ex;
#pragma unroll
        for (int off = 32; off; off >>= 1) sum += __shfl_xor(sum, off);
        if (f < F) out[(size_t)n * F + f] = vv - m - logf(sum);
    }
}

extern "C" void kernel_launch(void* const* d_in, const int* in_sizes, int n_in,
                              void* d_out, int out_size, void* d_ws, size_t ws_size,
                              hipStream_t stream) {
    const float* x  = (const float*)d_in[0];
    const void*  ei = d_in[1];
    const float* W1 = (const float*)d_in[2];
    const float* b1 = (const float*)d_in[3];
    const float* W2 = (const float*)d_in[4];
    const float* b2 = (const float*)d_in[5];
    const float* W3 = (const float*)d_in[6];
    const float* b3 = (const float*)d_in[7];
    float* out = (float*)d_out;

    char* ws = (char*)d_ws;
    size_t off = 0;
    auto alloc = [&](size_t bytes) { void* p = ws + off; off += (bytes + 255) & ~255ULL; return p; };
    int*   deg    = (int*)alloc(NN * 4);
    float* dis    = (float*)alloc(NN * 4);
    int*   offs   = (int*)alloc(NN * 4);
    int*   cursor = (int*)alloc(NN * 4);
    int*   bsum   = (int*)alloc(512 * 4);
    int*   flag   = (int*)alloc(4);
    int2*  csr    = (int2*)alloc((size_t)NE * 8);
    float* bufA   = (float*)alloc((size_t)NN * 64 * 4);
    float* bufB   = (float*)alloc((size_t)NN * 64 * 4);

    const int nblk = (NN + 255) / 256;

    // CSR build
    k_detect<<<1, 64, 0, stream>>>((const int*)ei, flag);
    k_deg_init<<<nblk, 256, 0, stream>>>(deg);
    k_deg_count<<<(NE + 255) / 256, 256, 0, stream>>>(ei, flag, deg);
    k_dis<<<nblk, 256, 0, stream>>>(deg, dis);
    k_scan1<<<SCAN_BLOCKS, 256, 0, stream>>>(deg, offs, bsum);
    k_scan2<<<1, 512, 0, stream>>>(bsum);
    k_scan3<<<SCAN_BLOCKS, 256, 0, stream>>>(offs, bsum, cursor);
    k_place<<<(NE + 255) / 256, 256, 0, stream>>>(ei, flag, dis, cursor, csr);

    const int gemm_grid = (NN + 3) / 4;

    // layer 1: h1 = Agg(x@W1) + b1   (ReLU fused into next gemm's load)
    k_gemm<128, 64, false><<<gemm_grid, 256, 0, stream>>>(x, W1, bufA);
    k_gather<64, false><<<gemm_grid, 256, 0, stream>>>(offs, deg, csr, dis, bufA, b1, bufB);

    // layer 2
    k_gemm<64, 64, true><<<gemm_grid, 256, 0, stream>>>(bufB, W2, bufA);
    k_gather<64, false><<<gemm_grid, 256, 0, stream>>>(offs, deg, csr, dis, bufA, b2, bufB);

    // layer 3 + fused log_softmax
    k_gemm<64, 40, true><<<gemm_grid, 256, 0, stream>>>(bufB, W3, bufA);
    k_gather<40, true><<<gemm_grid, 256, 0, stream>>>(offs, deg, csr, dis, bufA, b3, out);
}

// Round 3
// 572.690 us; speedup vs baseline: 2.5734x; 1.4565x over previous
//
#include <hip/hip_runtime.h>
#include <cstdint>
#include <cstddef>
#include <math.h>

#define NN 100000
#define NE 1600000
#define SCAN_BLOCKS ((NN + 255) / 256)   // 391

// GEMM tiling
#define GB_NODES 256     // nodes per block
#define GB_KC 32         // K-chunk
#define GB_STRIDE 260    // GB_NODES + 4 (pad: keeps b128 alignment, spreads banks)

// ---------- index-width detection (int64 vs int32 edge_index) ----------
__global__ __launch_bounds__(64) void k_detect(const int* __restrict__ p, int* flag) {
    int nz = 0;
    for (int i = threadIdx.x; i < 1024; i += 64) nz |= (p[2 * i + 1] != 0);
    unsigned long long b = __ballot(nz != 0);
    if (threadIdx.x == 0) *flag = (b == 0ULL) ? 1 : 0;  // 1 => int64
}

__device__ __forceinline__ int load_idx(const void* ei, int isI64, int pos) {
    if (isI64) return (int)((const long long*)ei)[pos];
    return ((const int*)ei)[pos];
}

// ---------- degree / norm ----------
__global__ __launch_bounds__(256) void k_deg_init(int* deg) {
    int i = blockIdx.x * 256 + threadIdx.x;
    if (i < NN) deg[i] = 0;  // in-edges only; self-loop handled analytically
}

__global__ __launch_bounds__(256) void k_deg_count(const void* __restrict__ ei,
                                                   const int* __restrict__ flag, int* deg) {
    int e = blockIdx.x * 256 + threadIdx.x;
    if (e < NE) {
        int isI64 = *flag;
        atomicAdd(&deg[load_idx(ei, isI64, NE + e)], 1);
    }
}

__global__ __launch_bounds__(256) void k_dis(const int* __restrict__ deg, float* dis) {
    int i = blockIdx.x * 256 + threadIdx.x;
    if (i < NN) dis[i] = rsqrtf((float)(deg[i] + 1));  // +1 self-loop
}

// ---------- exclusive scan of deg -> offs (3-phase) ----------
__global__ __launch_bounds__(256) void k_scan1(const int* __restrict__ deg,
                                               int* __restrict__ offs, int* __restrict__ bsum) {
    __shared__ int tmp[256];
    int i = blockIdx.x * 256 + threadIdx.x;
    int v = (i < NN) ? deg[i] : 0;
    tmp[threadIdx.x] = v;
    __syncthreads();
#pragma unroll
    for (int off = 1; off < 256; off <<= 1) {
        int t = (threadIdx.x >= off) ? tmp[threadIdx.x - off] : 0;
        __syncthreads();
        tmp[threadIdx.x] += t;
        __syncthreads();
    }
    if (i < NN) offs[i] = tmp[threadIdx.x] - v;
    if (threadIdx.x == 255) bsum[blockIdx.x] = tmp[255];
}

__global__ __launch_bounds__(512) void k_scan2(int* __restrict__ bsum) {
    __shared__ int tmp[512];
    int v = (threadIdx.x < SCAN_BLOCKS) ? bsum[threadIdx.x] : 0;
    tmp[threadIdx.x] = v;
    __syncthreads();
#pragma unroll
    for (int off = 1; off < 512; off <<= 1) {
        int t = (threadIdx.x >= off) ? tmp[threadIdx.x - off] : 0;
        __syncthreads();
        tmp[threadIdx.x] += t;
        __syncthreads();
    }
    if (threadIdx.x < SCAN_BLOCKS) bsum[threadIdx.x] = tmp[threadIdx.x] - v;
}

__global__ __launch_bounds__(256) void k_scan3(int* __restrict__ offs,
                                               const int* __restrict__ bsum,
                                               int* __restrict__ cursor) {
    int i = blockIdx.x * 256 + threadIdx.x;
    if (i < NN) {
        int o = offs[i] + bsum[blockIdx.x];
        offs[i] = o;
        cursor[i] = o;
    }
}

// ---------- CSR placement: csr[slot] = {src, dis[src]} ----------
__global__ __launch_bounds__(256) void k_place(const void* __restrict__ ei,
                                               const int* __restrict__ flag,
                                               const float* __restrict__ dis,
                                               int* cursor, int2* __restrict__ csr) {
    int e = blockIdx.x * 256 + threadIdx.x;
    if (e >= NE) return;
    int isI64 = *flag;
    int s = load_idx(ei, isI64, e);
    int d = load_idx(ei, isI64, NE + e);
    int slot = atomicAdd(&cursor[d], 1);
    int2 pk;
    pk.x = s;
    pk.y = __float_as_int(dis[s]);
    csr[slot] = pk;
}

// ---------- register-tiled GEMM ----------
// out[N][FR] = act(x)[N][K] @ W[K][FR]. Block = 256 threads, 256 nodes.
// Thread (r=tid>>3, c=tid&7) computes nodes r*8..r*8+7 x features c*8..c*8+7.
// x staged TRANSPOSED in LDS (xT[k][node]) so operand reads are ds_read_b128:
// per k-step 4 b128 feed 64 FMAs (vs 1 b32 per FMA in the old wave-per-node form).
// FR=40 pads the W tile to 64 with zeros; c>=5 threads compute-but-don't-write.
template <int K, int FR, bool RELU>
__global__ __launch_bounds__(256) void k_gemm(const float* __restrict__ x,
                                              const float* __restrict__ W,
                                              float* __restrict__ out) {
    __shared__ float xT[GB_KC * GB_STRIDE];   // 33,280 B
    __shared__ float Wc[GB_KC * 64];          //  8,192 B
    const int tid = threadIdx.x;
    const int r = tid >> 3;   // 0..31
    const int c = tid & 7;    // 0..7
    const int nrow = tid >> 3;
    const int f4 = tid & 7;
    const int nbase = blockIdx.x * GB_NODES;

    float acc[8][8];
#pragma unroll
    for (int i = 0; i < 8; ++i)
#pragma unroll
        for (int j = 0; j < 8; ++j) acc[i][j] = 0.f;

    for (int kc = 0; kc < K; kc += GB_KC) {
        // stage W chunk (zero-pad features >= FR)
#pragma unroll
        for (int q = 0; q < 8; ++q) {
            int e = q * 256 + tid;
            int kk = e >> 6, j = e & 63;
            Wc[kk * 64 + j] = (j < FR) ? W[(size_t)(kc + kk) * FR + j] : 0.f;
        }
        // stage x chunk transposed: 256 nodes x 32 k
#pragma unroll
        for (int q = 0; q < 8; ++q) {
            int nl = q * 32 + nrow;
            int n = nbase + nl;
            float4 v = make_float4(0.f, 0.f, 0.f, 0.f);
            if (n < NN) v = *(const float4*)(x + (size_t)n * K + kc + f4 * 4);
            if (RELU) {
                v.x = fmaxf(v.x, 0.f); v.y = fmaxf(v.y, 0.f);
                v.z = fmaxf(v.z, 0.f); v.w = fmaxf(v.w, 0.f);
            }
            xT[(f4 * 4 + 0) * GB_STRIDE + nl] = v.x;
            xT[(f4 * 4 + 1) * GB_STRIDE + nl] = v.y;
            xT[(f4 * 4 + 2) * GB_STRIDE + nl] = v.z;
            xT[(f4 * 4 + 3) * GB_STRIDE + nl] = v.w;
        }
        __syncthreads();
#pragma unroll 4
        for (int kk = 0; kk < GB_KC; ++kk) {
            const float* xr = &xT[kk * GB_STRIDE + r * 8];
            float4 a0 = *(const float4*)xr;
            float4 a1 = *(const float4*)(xr + 4);
            const float* wr = &Wc[kk * 64 + c * 8];
            float4 w0 = *(const float4*)wr;
            float4 w1 = *(const float4*)(wr + 4);
            float xa[8] = {a0.x, a0.y, a0.z, a0.w, a1.x, a1.y, a1.z, a1.w};
            float wb[8] = {w0.x, w0.y, w0.z, w0.w, w1.x, w1.y, w1.z, w1.w};
#pragma unroll
            for (int i = 0; i < 8; ++i)
#pragma unroll
                for (int j = 0; j < 8; ++j)
                    acc[i][j] = fmaf(xa[i], wb[j], acc[i][j]);
        }
        __syncthreads();
    }
    if (c * 8 < FR) {
#pragma unroll
        for (int i = 0; i < 8; ++i) {
            int n = nbase + r * 8 + i;
            if (n < NN) {
                float4 o0 = make_float4(acc[i][0], acc[i][1], acc[i][2], acc[i][3]);
                float4 o1 = make_float4(acc[i][4], acc[i][5], acc[i][6], acc[i][7]);
                *(float4*)(out + (size_t)n * FR + c * 8) = o0;
                *(float4*)(out + (size_t)n * FR + c * 8 + 4) = o1;
            }
        }
    }
}

// ---------- gather aggregation: one wave per node ----------
// out[n][f] = dis[n] * ( sum_e dis[src_e]*h[src_e][f] + dis[n]*h[n][f] ) + b[f]
template <int F, bool SOFTMAX>
__global__ __launch_bounds__(256) void k_gather(const int* __restrict__ offs,
                                                const int* __restrict__ deg,
                                                const int2* __restrict__ csr,
                                                const float* __restrict__ dis,
                                                const float* __restrict__ h,
                                                const float* __restrict__ b,
                                                float* __restrict__ out) {
    int n = blockIdx.x * 4 + (threadIdx.x >> 6);
    int f = threadIdx.x & 63;
    if (n >= NN) return;
    int fc = (f < F) ? f : 0;  // clamp so inactive lanes read valid addrs
    float dv = dis[n];
    float acc = dv * h[(size_t)n * F + fc];  // self-loop term
    int start = offs[n];
    int len = deg[n];
    int i = 0;
    for (; i + 3 < len; i += 4) {
        int2 p0 = csr[start + i];
        int2 p1 = csr[start + i + 1];
        int2 p2 = csr[start + i + 2];
        int2 p3 = csr[start + i + 3];
        float h0 = h[(size_t)p0.x * F + fc];
        float h1 = h[(size_t)p1.x * F + fc];
        float h2 = h[(size_t)p2.x * F + fc];
        float h3 = h[(size_t)p3.x * F + fc];
        acc = fmaf(__int_as_float(p0.y), h0, acc);
        acc = fmaf(__int_as_float(p1.y), h1, acc);
        acc = fmaf(__int_as_float(p2.y), h2, acc);
        acc = fmaf(__int_as_float(p3.y), h3, acc);
    }
    for (; i < len; ++i) {
        int2 p0 = csr[start + i];
        acc = fmaf(__int_as_float(p0.y), h[(size_t)p0.x * F + fc], acc);
    }
    float v = dv * acc + b[fc];
    if (!SOFTMAX) {
        if (f < F) out[(size_t)n * F + f] = v;
    } else {
        float vv = (f < F) ? v : -INFINITY;
        float m = vv;
#pragma unroll
        for (int off = 32; off; off >>= 1) m = fmaxf(m, __shfl_xor(m, off));
        float ex = (f < F) ? __expf(vv - m) : 0.f;
        float sum = ex;
#pragma unroll
        for (int off = 32; off; off >>= 1) sum += __shfl_xor(sum, off);
        if (f < F) out[(size_t)n * F + f] = vv - m - logf(sum);
    }
}

extern "C" void kernel_launch(void* const* d_in, const int* in_sizes, int n_in,
                              void* d_out, int out_size, void* d_ws, size_t ws_size,
                              hipStream_t stream) {
    const float* x  = (const float*)d_in[0];
    const void*  ei = d_in[1];
    const float* W1 = (const float*)d_in[2];
    const float* b1 = (const float*)d_in[3];
    const float* W2 = (const float*)d_in[4];
    const float* b2 = (const float*)d_in[5];
    const float* W3 = (const float*)d_in[6];
    const float* b3 = (const float*)d_in[7];
    float* out = (float*)d_out;

    char* ws = (char*)d_ws;
    size_t off = 0;
    auto alloc = [&](size_t bytes) { void* p = ws + off; off += (bytes + 255) & ~255ULL; return p; };
    int*   deg    = (int*)alloc(NN * 4);
    float* dis    = (float*)alloc(NN * 4);
    int*   offs   = (int*)alloc(NN * 4);
    int*   cursor = (int*)alloc(NN * 4);
    int*   bsum   = (int*)alloc(512 * 4);
    int*   flag   = (int*)alloc(4);
    int2*  csr    = (int2*)alloc((size_t)NE * 8);
    float* bufA   = (float*)alloc((size_t)NN * 64 * 4);
    float* bufB   = (float*)alloc((size_t)NN * 64 * 4);

    const int nblk = (NN + 255) / 256;

    // CSR build
    k_detect<<<1, 64, 0, stream>>>((const int*)ei, flag);
    k_deg_init<<<nblk, 256, 0, stream>>>(deg);
    k_deg_count<<<(NE + 255) / 256, 256, 0, stream>>>(ei, flag, deg);
    k_dis<<<nblk, 256, 0, stream>>>(deg, dis);
    k_scan1<<<SCAN_BLOCKS, 256, 0, stream>>>(deg, offs, bsum);
    k_scan2<<<1, 512, 0, stream>>>(bsum);
    k_scan3<<<SCAN_BLOCKS, 256, 0, stream>>>(offs, bsum, cursor);
    k_place<<<(NE + 255) / 256, 256, 0, stream>>>(ei, flag, dis, cursor, csr);

    const int gemm_grid = (NN + GB_NODES - 1) / GB_NODES;   // 391
    const int gather_grid = (NN + 3) / 4;

    // layer 1: h1 = Agg(x@W1) + b1   (ReLU fused into next gemm's load)
    k_gemm<128, 64, false><<<gemm_grid, 256, 0, stream>>>(x, W1, bufA);
    k_gather<64, false><<<gather_grid, 256, 0, stream>>>(offs, deg, csr, dis, bufA, b1, bufB);

    // layer 2
    k_gemm<64, 64, true><<<gemm_grid, 256, 0, stream>>>(bufB, W2, bufA);
    k_gather<64, false><<<gather_grid, 256, 0, stream>>>(offs, deg, csr, dis, bufA, b2, bufB);

    // layer 3 + fused log_softmax
    k_gemm<64, 40, true><<<gemm_grid, 256, 0, stream>>>(bufB, W3, bufA);
    k_gather<40, true><<<gather_grid, 256, 0, stream>>>(offs, deg, csr, dis, bufA, b3, out);
}

// Round 4
// 450.973 us; speedup vs baseline: 3.2680x; 1.2699x over previous
//
#include <hip/hip_runtime.h>
#include <cstdint>
#include <cstddef>
#include <math.h>

#define NN 100000
#define NE 1600000
#define NB ((NN + 255) / 256)   // 391 node buckets (256 nodes each)
#define EB 400                  // phase-A edge blocks
#define EPB (NE / EB)           // 4000 edges per block

// GEMM tiling
#define GB_NODES 256
#define GB_KC 32
#define GB_STRIDE 260

// ---------- index-width detection (int64 vs int32 edge_index) ----------
__global__ __launch_bounds__(64) void k_detect(const int* __restrict__ p, int* flag) {
    int nz = 0;
    for (int i = threadIdx.x; i < 1024; i += 64) nz |= (p[2 * i + 1] != 0);
    unsigned long long b = __ballot(nz != 0);
    if (threadIdx.x == 0) *flag = (b == 0ULL) ? 1 : 0;  // 1 => int64
}

__device__ __forceinline__ int load_idx(const void* ei, int isI64, int pos) {
    if (isI64) return (int)((const long long*)ei)[pos];
    return ((const int*)ei)[pos];
}

// ---------- phase A1: per-block bucket histogram ----------
__global__ __launch_bounds__(256) void k_hist(const void* __restrict__ ei,
                                              const int* __restrict__ flag,
                                              int* __restrict__ counts) {
    __shared__ int h[NB];
    for (int i = threadIdx.x; i < NB; i += 256) h[i] = 0;
    __syncthreads();
    int isI64 = *flag;
    int base = blockIdx.x * EPB;
    for (int i = threadIdx.x; i < EPB; i += 256) {
        int d = load_idx(ei, isI64, NE + base + i);
        atomicAdd(&h[d >> 8], 1);
    }
    __syncthreads();
    for (int i = threadIdx.x; i < NB; i += 256) counts[blockIdx.x * NB + i] = h[i];
}

// ---------- phase A2: column prefix over blocks (one block per bucket) ----------
__global__ __launch_bounds__(512) void k_colscan(const int* __restrict__ counts,
                                                 int* __restrict__ pfx,
                                                 int* __restrict__ btot) {
    __shared__ int t[512];
    int j = blockIdx.x;
    int v = (threadIdx.x < EB) ? counts[threadIdx.x * NB + j] : 0;
    t[threadIdx.x] = v;
    __syncthreads();
#pragma unroll
    for (int off = 1; off < 512; off <<= 1) {
        int u = (threadIdx.x >= off) ? t[threadIdx.x - off] : 0;
        __syncthreads();
        t[threadIdx.x] += u;
        __syncthreads();
    }
    if (threadIdx.x < EB) pfx[threadIdx.x * NB + j] = t[threadIdx.x] - v;  // exclusive
    if (threadIdx.x == 511) btot[j] = t[511];
}

// ---------- phase A3: exclusive scan of bucket totals ----------
__global__ __launch_bounds__(512) void k_bucketscan(const int* __restrict__ btot,
                                                    int* __restrict__ bbase) {
    __shared__ int t[512];
    int v = (threadIdx.x < NB) ? btot[threadIdx.x] : 0;
    t[threadIdx.x] = v;
    __syncthreads();
#pragma unroll
    for (int off = 1; off < 512; off <<= 1) {
        int u = (threadIdx.x >= off) ? t[threadIdx.x - off] : 0;
        __syncthreads();
        t[threadIdx.x] += u;
        __syncthreads();
    }
    if (threadIdx.x < NB) bbase[threadIdx.x] = t[threadIdx.x] - v;
    if (threadIdx.x == 511) bbase[NB] = t[511];  // == NE
}

// ---------- phase A4: scatter edges into bucket regions (no global atomics) ----------
// entry = (dstlocal << 17) | src   (src < 2^17, dstlocal < 256)
__global__ __launch_bounds__(256) void k_scatter(const void* __restrict__ ei,
                                                 const int* __restrict__ flag,
                                                 const int* __restrict__ pfx,
                                                 const int* __restrict__ bbase,
                                                 int* __restrict__ csr_tmp) {
    __shared__ int basel[NB];
    __shared__ int cur[NB];
    for (int i = threadIdx.x; i < NB; i += 256) {
        basel[i] = bbase[i] + pfx[blockIdx.x * NB + i];
        cur[i] = 0;
    }
    __syncthreads();
    int isI64 = *flag;
    int base = blockIdx.x * EPB;
    for (int i = threadIdx.x; i < EPB; i += 256) {
        int s = load_idx(ei, isI64, base + i);
        int d = load_idx(ei, isI64, NE + base + i);
        int bkt = d >> 8;
        int slot = basel[bkt] + atomicAdd(&cur[bkt], 1);
        csr_tmp[slot] = ((d & 255) << 17) | s;
    }
}

// ---------- phase B: per-bucket counting sort -> final csr + deg/offs/dis ----------
__global__ __launch_bounds__(256) void k_sort(const int* __restrict__ bbase,
                                              const int* __restrict__ csr_tmp,
                                              int* __restrict__ csr,
                                              int* __restrict__ deg,
                                              int* __restrict__ offs,
                                              float* __restrict__ dis) {
    __shared__ int h[256];
    __shared__ int sc[256];
    __shared__ int cur[256];
    int j = blockIdx.x;
    int s0 = bbase[j], s1 = bbase[j + 1];
    h[threadIdx.x] = 0;
    __syncthreads();
    for (int p = s0 + threadIdx.x; p < s1; p += 256)
        atomicAdd(&h[csr_tmp[p] >> 17], 1);
    __syncthreads();
    int v = h[threadIdx.x];
    sc[threadIdx.x] = v;
    __syncthreads();
#pragma unroll
    for (int off = 1; off < 256; off <<= 1) {
        int u = (threadIdx.x >= off) ? sc[threadIdx.x - off] : 0;
        __syncthreads();
        sc[threadIdx.x] += u;
        __syncthreads();
    }
    int excl = sc[threadIdx.x] - v;
    int node = j * 256 + threadIdx.x;
    if (node < NN) {
        deg[node] = v;
        offs[node] = s0 + excl;
        dis[node] = rsqrtf((float)(v + 1));  // +1 self-loop
    }
    cur[threadIdx.x] = excl;
    __syncthreads();
    for (int p = s0 + threadIdx.x; p < s1; p += 256) {
        int pk = csr_tmp[p];
        int dl = pk >> 17;
        int pos = s0 + atomicAdd(&cur[dl], 1);
        csr[pos] = pk & 0x1FFFF;
    }
}

// ---------- register-tiled GEMM, epilogue scales rows by dis[n] ----------
// g[n][j] = dis[n] * (act(x)[n][:] @ W[:][j])
template <int K, int FR, bool RELU>
__global__ __launch_bounds__(256) void k_gemm(const float* __restrict__ x,
                                              const float* __restrict__ W,
                                              const float* __restrict__ dis,
                                              float* __restrict__ out) {
    __shared__ float xT[GB_KC * GB_STRIDE];
    __shared__ float Wc[GB_KC * 64];
    const int tid = threadIdx.x;
    const int r = tid >> 3;
    const int c = tid & 7;
    const int nrow = tid >> 3;
    const int f4 = tid & 7;
    const int nbase = blockIdx.x * GB_NODES;

    float acc[8][8];
#pragma unroll
    for (int i = 0; i < 8; ++i)
#pragma unroll
        for (int j = 0; j < 8; ++j) acc[i][j] = 0.f;

    for (int kc = 0; kc < K; kc += GB_KC) {
#pragma unroll
        for (int q = 0; q < 8; ++q) {
            int e = q * 256 + tid;
            int kk = e >> 6, j = e & 63;
            Wc[kk * 64 + j] = (j < FR) ? W[(size_t)(kc + kk) * FR + j] : 0.f;
        }
#pragma unroll
        for (int q = 0; q < 8; ++q) {
            int nl = q * 32 + nrow;
            int n = nbase + nl;
            float4 v = make_float4(0.f, 0.f, 0.f, 0.f);
            if (n < NN) v = *(const float4*)(x + (size_t)n * K + kc + f4 * 4);
            if (RELU) {
                v.x = fmaxf(v.x, 0.f); v.y = fmaxf(v.y, 0.f);
                v.z = fmaxf(v.z, 0.f); v.w = fmaxf(v.w, 0.f);
            }
            xT[(f4 * 4 + 0) * GB_STRIDE + nl] = v.x;
            xT[(f4 * 4 + 1) * GB_STRIDE + nl] = v.y;
            xT[(f4 * 4 + 2) * GB_STRIDE + nl] = v.z;
            xT[(f4 * 4 + 3) * GB_STRIDE + nl] = v.w;
        }
        __syncthreads();
#pragma unroll 4
        for (int kk = 0; kk < GB_KC; ++kk) {
            const float* xr = &xT[kk * GB_STRIDE + r * 8];
            float4 a0 = *(const float4*)xr;
            float4 a1 = *(const float4*)(xr + 4);
            const float* wr = &Wc[kk * 64 + c * 8];
            float4 w0 = *(const float4*)wr;
            float4 w1 = *(const float4*)(wr + 4);
            float xa[8] = {a0.x, a0.y, a0.z, a0.w, a1.x, a1.y, a1.z, a1.w};
            float wb[8] = {w0.x, w0.y, w0.z, w0.w, w1.x, w1.y, w1.z, w1.w};
#pragma unroll
            for (int i = 0; i < 8; ++i)
#pragma unroll
                for (int j = 0; j < 8; ++j)
                    acc[i][j] = fmaf(xa[i], wb[j], acc[i][j]);
        }
        __syncthreads();
    }
    if (c * 8 < FR) {
#pragma unroll
        for (int i = 0; i < 8; ++i) {
            int n = nbase + r * 8 + i;
            if (n < NN) {
                float dv = dis[n];
                float4 o0 = make_float4(dv * acc[i][0], dv * acc[i][1],
                                        dv * acc[i][2], dv * acc[i][3]);
                float4 o1 = make_float4(dv * acc[i][4], dv * acc[i][5],
                                        dv * acc[i][6], dv * acc[i][7]);
                *(float4*)(out + (size_t)n * FR + c * 8) = o0;
                *(float4*)(out + (size_t)n * FR + c * 8 + 4) = o1;
            }
        }
    }
}

// ---------- gather aggregation (unweighted sum of pre-scaled g) ----------
// out[n][f] = dis[n] * ( g[n][f] + sum_e g[src_e][f] ) + b[f]
template <int F, bool SOFTMAX>
__global__ __launch_bounds__(256) void k_gather(const int* __restrict__ offs,
                                                const int* __restrict__ deg,
                                                const int* __restrict__ csr,
                                                const float* __restrict__ dis,
                                                const float* __restrict__ g,
                                                const float* __restrict__ b,
                                                float* __restrict__ out) {
    int n = blockIdx.x * 4 + (threadIdx.x >> 6);
    int f = threadIdx.x & 63;
    if (n >= NN) return;
    int fc = (f < F) ? f : 0;
    float acc = g[(size_t)n * F + fc];  // self-loop (pre-scaled)
    int start = offs[n];
    int len = deg[n];
    int i = 0;
    for (; i + 3 < len; i += 4) {
        int s0 = csr[start + i];
        int s1 = csr[start + i + 1];
        int s2 = csr[start + i + 2];
        int s3 = csr[start + i + 3];
        float h0 = g[(size_t)s0 * F + fc];
        float h1 = g[(size_t)s1 * F + fc];
        float h2 = g[(size_t)s2 * F + fc];
        float h3 = g[(size_t)s3 * F + fc];
        acc += h0 + h1 + h2 + h3;
    }
    for (; i < len; ++i) acc += g[(size_t)csr[start + i] * F + fc];
    float v = dis[n] * acc + b[fc];
    if (!SOFTMAX) {
        if (f < F) out[(size_t)n * F + f] = v;
    } else {
        float vv = (f < F) ? v : -INFINITY;
        float m = vv;
#pragma unroll
        for (int off = 32; off; off >>= 1) m = fmaxf(m, __shfl_xor(m, off));
        float ex = (f < F) ? __expf(vv - m) : 0.f;
        float sum = ex;
#pragma unroll
        for (int off = 32; off; off >>= 1) sum += __shfl_xor(sum, off);
        if (f < F) out[(size_t)n * F + f] = vv - m - logf(sum);
    }
}

extern "C" void kernel_launch(void* const* d_in, const int* in_sizes, int n_in,
                              void* d_out, int out_size, void* d_ws, size_t ws_size,
                              hipStream_t stream) {
    const float* x  = (const float*)d_in[0];
    const void*  ei = d_in[1];
    const float* W1 = (const float*)d_in[2];
    const float* b1 = (const float*)d_in[3];
    const float* W2 = (const float*)d_in[4];
    const float* b2 = (const float*)d_in[5];
    const float* W3 = (const float*)d_in[6];
    const float* b3 = (const float*)d_in[7];
    float* out = (float*)d_out;

    char* ws = (char*)d_ws;
    size_t off = 0;
    auto alloc = [&](size_t bytes) { void* p = ws + off; off += (bytes + 255) & ~255ULL; return p; };
    int*   flag    = (int*)alloc(4);
    int*   counts  = (int*)alloc((size_t)EB * NB * 4);
    int*   pfx     = (int*)alloc((size_t)EB * NB * 4);
    int*   btot    = (int*)alloc(NB * 4);
    int*   bbase   = (int*)alloc((NB + 1) * 4);
    int*   deg     = (int*)alloc(NN * 4);
    float* dis     = (float*)alloc(NN * 4);
    int*   offs    = (int*)alloc(NN * 4);
    int*   csr_tmp = (int*)alloc((size_t)NE * 4);
    int*   csr     = (int*)alloc((size_t)NE * 4);
    float* bufA    = (float*)alloc((size_t)NN * 64 * 4);
    float* bufB    = (float*)alloc((size_t)NN * 64 * 4);

    // CSR build (deterministic two-phase counting sort; no global atomics)
    k_detect<<<1, 64, 0, stream>>>((const int*)ei, flag);
    k_hist<<<EB, 256, 0, stream>>>(ei, flag, counts);
    k_colscan<<<NB, 512, 0, stream>>>(counts, pfx, btot);
    k_bucketscan<<<1, 512, 0, stream>>>(btot, bbase);
    k_scatter<<<EB, 256, 0, stream>>>(ei, flag, pfx, bbase, csr_tmp);
    k_sort<<<NB, 256, 0, stream>>>(bbase, csr_tmp, csr, deg, offs, dis);

    const int gemm_grid = (NN + GB_NODES - 1) / GB_NODES;   // 391
    const int gather_grid = (NN + 3) / 4;

    // layer 1: g1 = dis*(x@W1); out1 = dis*(sum g1) + b1   (ReLU fused into next gemm)
    k_gemm<128, 64, false><<<gemm_grid, 256, 0, stream>>>(x, W1, dis, bufA);
    k_gather<64, false><<<gather_grid, 256, 0, stream>>>(offs, deg, csr, dis, bufA, b1, bufB);

    // layer 2
    k_gemm<64, 64, true><<<gemm_grid, 256, 0, stream>>>(bufB, W2, dis, bufA);
    k_gather<64, false><<<gather_grid, 256, 0, stream>>>(offs, deg, csr, dis, bufA, b2, bufB);

    // layer 3 + fused log_softmax
    k_gemm<64, 40, true><<<gemm_grid, 256, 0, stream>>>(bufB, W3, dis, bufA);
    k_gather<40, true><<<gather_grid, 256, 0, stream>>>(offs, deg, csr, dis, bufA, b3, out);
}

// Round 5
// 398.599 us; speedup vs baseline: 3.6974x; 1.1314x over previous
//
#include <hip/hip_runtime.h>
#include <cstdint>
#include <cstddef>
#include <math.h>

#define NN 100000
#define NE 1600000
#define NB ((NN + 255) / 256)   // 391 node buckets (256 nodes each)
#define EB 400                  // phase-A edge blocks
#define EPB (NE / EB)           // 4000 edges per block

// GEMM tiling
#define GB_NODES 256
#define GB_KC 32
#define GB_STRIDE 260

typedef unsigned short u16;

__device__ __forceinline__ float bf2f(u16 u) {
    union { unsigned int i; float f; } c; c.i = ((unsigned int)u) << 16; return c.f;
}
__device__ __forceinline__ u16 f2bf(float f) {  // round-to-nearest-even
    union { float f; unsigned int i; } c; c.f = f;
    unsigned int lsb = (c.i >> 16) & 1u;
    return (u16)((c.i + 0x7fffu + lsb) >> 16);
}
__device__ __forceinline__ unsigned int pack2(float a, float b) {
    return (unsigned int)f2bf(a) | ((unsigned int)f2bf(b) << 16);
}

// ---------- index-width detection (int64 vs int32 edge_index) ----------
__global__ __launch_bounds__(64) void k_detect(const int* __restrict__ p, int* flag) {
    int nz = 0;
    for (int i = threadIdx.x; i < 1024; i += 64) nz |= (p[2 * i + 1] != 0);
    unsigned long long b = __ballot(nz != 0);
    if (threadIdx.x == 0) *flag = (b == 0ULL) ? 1 : 0;  // 1 => int64
}

__device__ __forceinline__ int load_idx(const void* ei, int isI64, int pos) {
    if (isI64) return (int)((const long long*)ei)[pos];
    return ((const int*)ei)[pos];
}

// ---------- phase A1: per-block bucket histogram ----------
__global__ __launch_bounds__(256) void k_hist(const void* __restrict__ ei,
                                              const int* __restrict__ flag,
                                              int* __restrict__ counts) {
    __shared__ int h[NB];
    for (int i = threadIdx.x; i < NB; i += 256) h[i] = 0;
    __syncthreads();
    int isI64 = *flag;
    int base = blockIdx.x * EPB;
    for (int i = threadIdx.x; i < EPB; i += 256) {
        int d = load_idx(ei, isI64, NE + base + i);
        atomicAdd(&h[d >> 8], 1);
    }
    __syncthreads();
    for (int i = threadIdx.x; i < NB; i += 256) counts[blockIdx.x * NB + i] = h[i];
}

// ---------- phase A2: column prefix over blocks (one block per bucket) ----------
__global__ __launch_bounds__(512) void k_colscan(const int* __restrict__ counts,
                                                 int* __restrict__ pfx,
                                                 int* __restrict__ btot) {
    __shared__ int t[512];
    int j = blockIdx.x;
    int v = (threadIdx.x < EB) ? counts[threadIdx.x * NB + j] : 0;
    t[threadIdx.x] = v;
    __syncthreads();
#pragma unroll
    for (int off = 1; off < 512; off <<= 1) {
        int u = (threadIdx.x >= off) ? t[threadIdx.x - off] : 0;
        __syncthreads();
        t[threadIdx.x] += u;
        __syncthreads();
    }
    if (threadIdx.x < EB) pfx[threadIdx.x * NB + j] = t[threadIdx.x] - v;  // exclusive
    if (threadIdx.x == 511) btot[j] = t[511];
}

// ---------- phase A3: exclusive scan of bucket totals ----------
__global__ __launch_bounds__(512) void k_bucketscan(const int* __restrict__ btot,
                                                    int* __restrict__ bbase) {
    __shared__ int t[512];
    int v = (threadIdx.x < NB) ? btot[threadIdx.x] : 0;
    t[threadIdx.x] = v;
    __syncthreads();
#pragma unroll
    for (int off = 1; off < 512; off <<= 1) {
        int u = (threadIdx.x >= off) ? t[threadIdx.x - off] : 0;
        __syncthreads();
        t[threadIdx.x] += u;
        __syncthreads();
    }
    if (threadIdx.x < NB) bbase[threadIdx.x] = t[threadIdx.x] - v;
    if (threadIdx.x == 511) bbase[NB] = t[511];  // == NE
}

// ---------- phase A4: scatter edges into bucket regions (no global atomics) ----------
// entry = (dstlocal << 17) | src   (src < 2^17, dstlocal < 256)
__global__ __launch_bounds__(256) void k_scatter(const void* __restrict__ ei,
                                                 const int* __restrict__ flag,
                                                 const int* __restrict__ pfx,
                                                 const int* __restrict__ bbase,
                                                 int* __restrict__ csr_tmp) {
    __shared__ int basel[NB];
    __shared__ int cur[NB];
    for (int i = threadIdx.x; i < NB; i += 256) {
        basel[i] = bbase[i] + pfx[blockIdx.x * NB + i];
        cur[i] = 0;
    }
    __syncthreads();
    int isI64 = *flag;
    int base = blockIdx.x * EPB;
    for (int i = threadIdx.x; i < EPB; i += 256) {
        int s = load_idx(ei, isI64, base + i);
        int d = load_idx(ei, isI64, NE + base + i);
        int bkt = d >> 8;
        int slot = basel[bkt] + atomicAdd(&cur[bkt], 1);
        csr_tmp[slot] = ((d & 255) << 17) | s;
    }
}

// ---------- phase B: per-bucket counting sort -> final csr + deg/offs/dis ----------
__global__ __launch_bounds__(256) void k_sort(const int* __restrict__ bbase,
                                              const int* __restrict__ csr_tmp,
                                              int* __restrict__ csr,
                                              int* __restrict__ deg,
                                              int* __restrict__ offs,
                                              float* __restrict__ dis) {
    __shared__ int h[256];
    __shared__ int sc[256];
    __shared__ int cur[256];
    int j = blockIdx.x;
    int s0 = bbase[j], s1 = bbase[j + 1];
    h[threadIdx.x] = 0;
    __syncthreads();
    for (int p = s0 + threadIdx.x; p < s1; p += 256)
        atomicAdd(&h[csr_tmp[p] >> 17], 1);
    __syncthreads();
    int v = h[threadIdx.x];
    sc[threadIdx.x] = v;
    __syncthreads();
#pragma unroll
    for (int off = 1; off < 256; off <<= 1) {
        int u = (threadIdx.x >= off) ? sc[threadIdx.x - off] : 0;
        __syncthreads();
        sc[threadIdx.x] += u;
        __syncthreads();
    }
    int excl = sc[threadIdx.x] - v;
    int node = j * 256 + threadIdx.x;
    if (node < NN) {
        deg[node] = v;
        offs[node] = s0 + excl;
        dis[node] = rsqrtf((float)(v + 1));  // +1 self-loop
    }
    cur[threadIdx.x] = excl;
    __syncthreads();
    for (int p = s0 + threadIdx.x; p < s1; p += 256) {
        int pk = csr_tmp[p];
        int dl = pk >> 17;
        int pos = s0 + atomicAdd(&cur[dl], 1);
        csr[pos] = pk & 0x1FFFF;
    }
}

// ---------- register-tiled GEMM, epilogue scales rows by dis[n], writes bf16 ----------
// g[n][j] = bf16( dis[n] * (act(x)[n][:] @ W[:][j]) )
template <int K, int FR, bool RELU>
__global__ __launch_bounds__(256) void k_gemm(const float* __restrict__ x,
                                              const float* __restrict__ W,
                                              const float* __restrict__ dis,
                                              u16* __restrict__ out) {
    __shared__ float xT[GB_KC * GB_STRIDE];
    __shared__ float Wc[GB_KC * 64];
    const int tid = threadIdx.x;
    const int r = tid >> 3;
    const int c = tid & 7;
    const int nrow = tid >> 3;
    const int f4 = tid & 7;
    const int nbase = blockIdx.x * GB_NODES;

    float acc[8][8];
#pragma unroll
    for (int i = 0; i < 8; ++i)
#pragma unroll
        for (int j = 0; j < 8; ++j) acc[i][j] = 0.f;

    for (int kc = 0; kc < K; kc += GB_KC) {
#pragma unroll
        for (int q = 0; q < 8; ++q) {
            int e = q * 256 + tid;
            int kk = e >> 6, j = e & 63;
            Wc[kk * 64 + j] = (j < FR) ? W[(size_t)(kc + kk) * FR + j] : 0.f;
        }
#pragma unroll
        for (int q = 0; q < 8; ++q) {
            int nl = q * 32 + nrow;
            int n = nbase + nl;
            float4 v = make_float4(0.f, 0.f, 0.f, 0.f);
            if (n < NN) v = *(const float4*)(x + (size_t)n * K + kc + f4 * 4);
            if (RELU) {
                v.x = fmaxf(v.x, 0.f); v.y = fmaxf(v.y, 0.f);
                v.z = fmaxf(v.z, 0.f); v.w = fmaxf(v.w, 0.f);
            }
            xT[(f4 * 4 + 0) * GB_STRIDE + nl] = v.x;
            xT[(f4 * 4 + 1) * GB_STRIDE + nl] = v.y;
            xT[(f4 * 4 + 2) * GB_STRIDE + nl] = v.z;
            xT[(f4 * 4 + 3) * GB_STRIDE + nl] = v.w;
        }
        __syncthreads();
#pragma unroll 4
        for (int kk = 0; kk < GB_KC; ++kk) {
            const float* xr = &xT[kk * GB_STRIDE + r * 8];
            float4 a0 = *(const float4*)xr;
            float4 a1 = *(const float4*)(xr + 4);
            const float* wr = &Wc[kk * 64 + c * 8];
            float4 w0 = *(const float4*)wr;
            float4 w1 = *(const float4*)(wr + 4);
            float xa[8] = {a0.x, a0.y, a0.z, a0.w, a1.x, a1.y, a1.z, a1.w};
            float wb[8] = {w0.x, w0.y, w0.z, w0.w, w1.x, w1.y, w1.z, w1.w};
#pragma unroll
            for (int i = 0; i < 8; ++i)
#pragma unroll
                for (int j = 0; j < 8; ++j)
                    acc[i][j] = fmaf(xa[i], wb[j], acc[i][j]);
        }
        __syncthreads();
    }
    if (c * 8 < FR) {
#pragma unroll
        for (int i = 0; i < 8; ++i) {
            int n = nbase + r * 8 + i;
            if (n < NN) {
                float dv = dis[n];
                uint4 o;
                o.x = pack2(dv * acc[i][0], dv * acc[i][1]);
                o.y = pack2(dv * acc[i][2], dv * acc[i][3]);
                o.z = pack2(dv * acc[i][4], dv * acc[i][5]);
                o.w = pack2(dv * acc[i][6], dv * acc[i][7]);
                *(uint4*)(out + (size_t)n * FR + c * 8) = o;
            }
        }
    }
}

// ---------- gather aggregation (unweighted sum of pre-scaled bf16 g) ----------
// out[n][f] = dis[n] * ( g[n][f] + sum_e g[src_e][f] ) + b[f]
template <int F, bool SOFTMAX>
__global__ __launch_bounds__(256) void k_gather(const int* __restrict__ offs,
                                                const int* __restrict__ deg,
                                                const int* __restrict__ csr,
                                                const float* __restrict__ dis,
                                                const u16* __restrict__ g,
                                                const float* __restrict__ b,
                                                float* __restrict__ out) {
    int n = blockIdx.x * 4 + (threadIdx.x >> 6);
    int f = threadIdx.x & 63;
    if (n >= NN) return;
    int fc = (f < F) ? f : 0;
    float acc = bf2f(g[(size_t)n * F + fc]);  // self-loop (pre-scaled)
    int start = offs[n];
    int len = deg[n];
    int i = 0;
    for (; i + 7 < len; i += 8) {
        int s0 = csr[start + i];
        int s1 = csr[start + i + 1];
        int s2 = csr[start + i + 2];
        int s3 = csr[start + i + 3];
        int s4 = csr[start + i + 4];
        int s5 = csr[start + i + 5];
        int s6 = csr[start + i + 6];
        int s7 = csr[start + i + 7];
        u16 h0 = g[(size_t)s0 * F + fc];
        u16 h1 = g[(size_t)s1 * F + fc];
        u16 h2 = g[(size_t)s2 * F + fc];
        u16 h3 = g[(size_t)s3 * F + fc];
        u16 h4 = g[(size_t)s4 * F + fc];
        u16 h5 = g[(size_t)s5 * F + fc];
        u16 h6 = g[(size_t)s6 * F + fc];
        u16 h7 = g[(size_t)s7 * F + fc];
        acc += bf2f(h0) + bf2f(h1) + bf2f(h2) + bf2f(h3)
             + bf2f(h4) + bf2f(h5) + bf2f(h6) + bf2f(h7);
    }
    for (; i + 1 < len; i += 2) {
        int s0 = csr[start + i];
        int s1 = csr[start + i + 1];
        u16 h0 = g[(size_t)s0 * F + fc];
        u16 h1 = g[(size_t)s1 * F + fc];
        acc += bf2f(h0) + bf2f(h1);
    }
    if (i < len) acc += bf2f(g[(size_t)csr[start + i] * F + fc]);
    float v = dis[n] * acc + b[fc];
    if (!SOFTMAX) {
        if (f < F) out[(size_t)n * F + f] = v;
    } else {
        float vv = (f < F) ? v : -INFINITY;
        float m = vv;
#pragma unroll
        for (int off = 32; off; off >>= 1) m = fmaxf(m, __shfl_xor(m, off));
        float ex = (f < F) ? __expf(vv - m) : 0.f;
        float sum = ex;
#pragma unroll
        for (int off = 32; off; off >>= 1) sum += __shfl_xor(sum, off);
        if (f < F) out[(size_t)n * F + f] = vv - m - logf(sum);
    }
}

extern "C" void kernel_launch(void* const* d_in, const int* in_sizes, int n_in,
                              void* d_out, int out_size, void* d_ws, size_t ws_size,
                              hipStream_t stream) {
    const float* x  = (const float*)d_in[0];
    const void*  ei = d_in[1];
    const float* W1 = (const float*)d_in[2];
    const float* b1 = (const float*)d_in[3];
    const float* W2 = (const float*)d_in[4];
    const float* b2 = (const float*)d_in[5];
    const float* W3 = (const float*)d_in[6];
    const float* b3 = (const float*)d_in[7];
    float* out = (float*)d_out;

    char* ws = (char*)d_ws;
    size_t off = 0;
    auto alloc = [&](size_t bytes) { void* p = ws + off; off += (bytes + 255) & ~255ULL; return p; };
    int*   flag    = (int*)alloc(4);
    int*   counts  = (int*)alloc((size_t)EB * NB * 4);
    int*   pfx     = (int*)alloc((size_t)EB * NB * 4);
    int*   btot    = (int*)alloc(NB * 4);
    int*   bbase   = (int*)alloc((NB + 1) * 4);
    int*   deg     = (int*)alloc(NN * 4);
    float* dis     = (float*)alloc(NN * 4);
    int*   offs    = (int*)alloc(NN * 4);
    int*   csr_tmp = (int*)alloc((size_t)NE * 4);
    int*   csr     = (int*)alloc((size_t)NE * 4);
    u16*   gbuf    = (u16*)alloc((size_t)NN * 64 * 2);   // bf16 staging (12.8 MB)
    float* act     = (float*)alloc((size_t)NN * 64 * 4); // fp32 inter-layer activations

    // CSR build (deterministic two-phase counting sort; no global atomics)
    k_detect<<<1, 64, 0, stream>>>((const int*)ei, flag);
    k_hist<<<EB, 256, 0, stream>>>(ei, flag, counts);
    k_colscan<<<NB, 512, 0, stream>>>(counts, pfx, btot);
    k_bucketscan<<<1, 512, 0, stream>>>(btot, bbase);
    k_scatter<<<EB, 256, 0, stream>>>(ei, flag, pfx, bbase, csr_tmp);
    k_sort<<<NB, 256, 0, stream>>>(bbase, csr_tmp, csr, deg, offs, dis);

    const int gemm_grid = (NN + GB_NODES - 1) / GB_NODES;   // 391
    const int gather_grid = (NN + 3) / 4;

    // layer 1: g1 = bf16(dis*(x@W1)); out1 = dis*(sum g1) + b1  (ReLU fused into next gemm)
    k_gemm<128, 64, false><<<gemm_grid, 256, 0, stream>>>(x, W1, dis, gbuf);
    k_gather<64, false><<<gather_grid, 256, 0, stream>>>(offs, deg, csr, dis, gbuf, b1, act);

    // layer 2
    k_gemm<64, 64, true><<<gemm_grid, 256, 0, stream>>>(act, W2, dis, gbuf);
    k_gather<64, false><<<gather_grid, 256, 0, stream>>>(offs, deg, csr, dis, gbuf, b2, act);

    // layer 3 + fused log_softmax
    k_gemm<64, 40, true><<<gemm_grid, 256, 0, stream>>>(act, W3, dis, gbuf);
    k_gather<40, true><<<gather_grid, 256, 0, stream>>>(offs, deg, csr, dis, gbuf, b3, out);
}

// Round 6
// 360.087 us; speedup vs baseline: 4.0929x; 1.1070x over previous
//
#include <hip/hip_runtime.h>
#include <cstdint>
#include <cstddef>
#include <math.h>

#define NN 100000
#define NE 1600000
#define NB ((NN + 255) / 256)   // 391 node buckets (256 nodes each)
#define EB 400                  // phase-A edge blocks
#define EPB (NE / EB)           // 4000 edges per block

// GEMM tiling
#define GB_NODES 256
#define GB_KC 32
#define GB_STRIDE 260

typedef unsigned short u16;

__device__ __forceinline__ float bf2f(u16 u) {
    union { unsigned int i; float f; } c; c.i = ((unsigned int)u) << 16; return c.f;
}
__device__ __forceinline__ u16 f2bf(float f) {  // round-to-nearest-even
    union { float f; unsigned int i; } c; c.f = f;
    unsigned int lsb = (c.i >> 16) & 1u;
    return (u16)((c.i + 0x7fffu + lsb) >> 16);
}
__device__ __forceinline__ unsigned int pack2(float a, float b) {
    return (unsigned int)f2bf(a) | ((unsigned int)f2bf(b) << 16);
}

// ---------- index-width detection (int64 vs int32 edge_index) ----------
__global__ __launch_bounds__(64) void k_detect(const int* __restrict__ p, int* flag) {
    int nz = 0;
    for (int i = threadIdx.x; i < 1024; i += 64) nz |= (p[2 * i + 1] != 0);
    unsigned long long b = __ballot(nz != 0);
    if (threadIdx.x == 0) *flag = (b == 0ULL) ? 1 : 0;  // 1 => int64
}

__device__ __forceinline__ int load_idx(const void* ei, int isI64, int pos) {
    if (isI64) return (int)((const long long*)ei)[pos];
    return ((const int*)ei)[pos];
}

// ---------- phase A1: per-block bucket histogram ----------
__global__ __launch_bounds__(256) void k_hist(const void* __restrict__ ei,
                                              const int* __restrict__ flag,
                                              int* __restrict__ counts) {
    __shared__ int h[NB];
    for (int i = threadIdx.x; i < NB; i += 256) h[i] = 0;
    __syncthreads();
    int isI64 = *flag;
    int base = blockIdx.x * EPB;
    for (int i = threadIdx.x; i < EPB; i += 256) {
        int d = load_idx(ei, isI64, NE + base + i);
        atomicAdd(&h[d >> 8], 1);
    }
    __syncthreads();
    for (int i = threadIdx.x; i < NB; i += 256) counts[blockIdx.x * NB + i] = h[i];
}

// ---------- phase A2: column prefix over blocks (one block per bucket) ----------
__global__ __launch_bounds__(512) void k_colscan(const int* __restrict__ counts,
                                                 int* __restrict__ pfx,
                                                 int* __restrict__ btot) {
    __shared__ int t[512];
    int j = blockIdx.x;
    int v = (threadIdx.x < EB) ? counts[threadIdx.x * NB + j] : 0;
    t[threadIdx.x] = v;
    __syncthreads();
#pragma unroll
    for (int off = 1; off < 512; off <<= 1) {
        int u = (threadIdx.x >= off) ? t[threadIdx.x - off] : 0;
        __syncthreads();
        t[threadIdx.x] += u;
        __syncthreads();
    }
    if (threadIdx.x < EB) pfx[threadIdx.x * NB + j] = t[threadIdx.x] - v;  // exclusive
    if (threadIdx.x == 511) btot[j] = t[511];
}

// ---------- phase A3: exclusive scan of bucket totals ----------
__global__ __launch_bounds__(512) void k_bucketscan(const int* __restrict__ btot,
                                                    int* __restrict__ bbase) {
    __shared__ int t[512];
    int v = (threadIdx.x < NB) ? btot[threadIdx.x] : 0;
    t[threadIdx.x] = v;
    __syncthreads();
#pragma unroll
    for (int off = 1; off < 512; off <<= 1) {
        int u = (threadIdx.x >= off) ? t[threadIdx.x - off] : 0;
        __syncthreads();
        t[threadIdx.x] += u;
        __syncthreads();
    }
    if (threadIdx.x < NB) bbase[threadIdx.x] = t[threadIdx.x] - v;
    if (threadIdx.x == 511) bbase[NB] = t[511];  // == NE
}

// ---------- phase A4: scatter edges into bucket regions (no global atomics) ----------
// entry = (dstlocal << 17) | src   (src < 2^17, dstlocal < 256)
__global__ __launch_bounds__(256) void k_scatter(const void* __restrict__ ei,
                                                 const int* __restrict__ flag,
                                                 const int* __restrict__ pfx,
                                                 const int* __restrict__ bbase,
                                                 int* __restrict__ csr_tmp) {
    __shared__ int basel[NB];
    __shared__ int cur[NB];
    for (int i = threadIdx.x; i < NB; i += 256) {
        basel[i] = bbase[i] + pfx[blockIdx.x * NB + i];
        cur[i] = 0;
    }
    __syncthreads();
    int isI64 = *flag;
    int base = blockIdx.x * EPB;
    for (int i = threadIdx.x; i < EPB; i += 256) {
        int s = load_idx(ei, isI64, base + i);
        int d = load_idx(ei, isI64, NE + base + i);
        int bkt = d >> 8;
        int slot = basel[bkt] + atomicAdd(&cur[bkt], 1);
        csr_tmp[slot] = ((d & 255) << 17) | s;
    }
}

// ---------- phase B: per-bucket counting sort -> final csr + deg/offs/dis ----------
__global__ __launch_bounds__(256) void k_sort(const int* __restrict__ bbase,
                                              const int* __restrict__ csr_tmp,
                                              int* __restrict__ csr,
                                              int* __restrict__ deg,
                                              int* __restrict__ offs,
                                              float* __restrict__ dis) {
    __shared__ int h[256];
    __shared__ int sc[256];
    __shared__ int cur[256];
    int j = blockIdx.x;
    int s0 = bbase[j], s1 = bbase[j + 1];
    h[threadIdx.x] = 0;
    __syncthreads();
    for (int p = s0 + threadIdx.x; p < s1; p += 256)
        atomicAdd(&h[csr_tmp[p] >> 17], 1);
    __syncthreads();
    int v = h[threadIdx.x];
    sc[threadIdx.x] = v;
    __syncthreads();
#pragma unroll
    for (int off = 1; off < 256; off <<= 1) {
        int u = (threadIdx.x >= off) ? sc[threadIdx.x - off] : 0;
        __syncthreads();
        sc[threadIdx.x] += u;
        __syncthreads();
    }
    int excl = sc[threadIdx.x] - v;
    int node = j * 256 + threadIdx.x;
    if (node < NN) {
        deg[node] = v;
        offs[node] = s0 + excl;
        dis[node] = rsqrtf((float)(v + 1));  // +1 self-loop
    }
    cur[threadIdx.x] = excl;
    __syncthreads();
    for (int p = s0 + threadIdx.x; p < s1; p += 256) {
        int pk = csr_tmp[p];
        int dl = pk >> 17;
        int pos = s0 + atomicAdd(&cur[dl], 1);
        csr[pos] = pk & 0x1FFFF;
    }
}

// ---------- register-tiled GEMM, epilogue scales rows by dis[n], writes bf16 ----------
// g[n][j] = bf16( dis[n] * (act(x)[n][:] @ W[:][j]) )
template <int K, int FR, bool RELU>
__global__ __launch_bounds__(256) void k_gemm(const float* __restrict__ x,
                                              const float* __restrict__ W,
                                              const float* __restrict__ dis,
                                              u16* __restrict__ out) {
    __shared__ float xT[GB_KC * GB_STRIDE];
    __shared__ float Wc[GB_KC * 64];
    const int tid = threadIdx.x;
    const int r = tid >> 3;
    const int c = tid & 7;
    const int nrow = tid >> 3;
    const int f4 = tid & 7;
    const int nbase = blockIdx.x * GB_NODES;

    float acc[8][8];
#pragma unroll
    for (int i = 0; i < 8; ++i)
#pragma unroll
        for (int j = 0; j < 8; ++j) acc[i][j] = 0.f;

    for (int kc = 0; kc < K; kc += GB_KC) {
#pragma unroll
        for (int q = 0; q < 8; ++q) {
            int e = q * 256 + tid;
            int kk = e >> 6, j = e & 63;
            Wc[kk * 64 + j] = (j < FR) ? W[(size_t)(kc + kk) * FR + j] : 0.f;
        }
#pragma unroll
        for (int q = 0; q < 8; ++q) {
            int nl = q * 32 + nrow;
            int n = nbase + nl;
            float4 v = make_float4(0.f, 0.f, 0.f, 0.f);
            if (n < NN) v = *(const float4*)(x + (size_t)n * K + kc + f4 * 4);
            if (RELU) {
                v.x = fmaxf(v.x, 0.f); v.y = fmaxf(v.y, 0.f);
                v.z = fmaxf(v.z, 0.f); v.w = fmaxf(v.w, 0.f);
            }
            xT[(f4 * 4 + 0) * GB_STRIDE + nl] = v.x;
            xT[(f4 * 4 + 1) * GB_STRIDE + nl] = v.y;
            xT[(f4 * 4 + 2) * GB_STRIDE + nl] = v.z;
            xT[(f4 * 4 + 3) * GB_STRIDE + nl] = v.w;
        }
        __syncthreads();
#pragma unroll 4
        for (int kk = 0; kk < GB_KC; ++kk) {
            const float* xr = &xT[kk * GB_STRIDE + r * 8];
            float4 a0 = *(const float4*)xr;
            float4 a1 = *(const float4*)(xr + 4);
            const float* wr = &Wc[kk * 64 + c * 8];
            float4 w0 = *(const float4*)wr;
            float4 w1 = *(const float4*)(wr + 4);
            float xa[8] = {a0.x, a0.y, a0.z, a0.w, a1.x, a1.y, a1.z, a1.w};
            float wb[8] = {w0.x, w0.y, w0.z, w0.w, w1.x, w1.y, w1.z, w1.w};
#pragma unroll
            for (int i = 0; i < 8; ++i)
#pragma unroll
                for (int j = 0; j < 8; ++j)
                    acc[i][j] = fmaf(xa[i], wb[j], acc[i][j]);
        }
        __syncthreads();
    }
    if (c * 8 < FR) {
#pragma unroll
        for (int i = 0; i < 8; ++i) {
            int n = nbase + r * 8 + i;
            if (n < NN) {
                float dv = dis[n];
                uint4 o;
                o.x = pack2(dv * acc[i][0], dv * acc[i][1]);
                o.y = pack2(dv * acc[i][2], dv * acc[i][3]);
                o.z = pack2(dv * acc[i][4], dv * acc[i][5]);
                o.w = pack2(dv * acc[i][6], dv * acc[i][7]);
                *(uint4*)(out + (size_t)n * FR + c * 8) = o;
            }
        }
    }
}

// ---------- gather aggregation (unweighted sum of pre-scaled bf16 g) ----------
// out[n][f] = dis[n] * ( g[n][f] + sum_e g[src_e][f] ) + b[f]
// csr indices forced wave-uniform scalar (s_load path); g addressed with
// 32-bit offsets from a uniform base (saddr global_load_ushort): ~3 VALU/edge.
template <int F, bool SOFTMAX>
__global__ __launch_bounds__(256) void k_gather(const int* __restrict__ offs,
                                                const int* __restrict__ deg,
                                                const int* __restrict__ csr,
                                                const float* __restrict__ dis,
                                                const u16* __restrict__ g,
                                                const float* __restrict__ b,
                                                float* __restrict__ out) {
    int n = blockIdx.x * 4 + (threadIdx.x >> 6);
    unsigned f = threadIdx.x & 63;
    if (n >= NN) return;
    unsigned fc = (f < (unsigned)F) ? f : 0u;
    int start = __builtin_amdgcn_readfirstlane(offs[n]);
    int len   = __builtin_amdgcn_readfirstlane(deg[n]);
    float dvn = dis[n];
    float bf  = b[fc];
    float acc = bf2f(g[(unsigned)n * F + fc]);  // self-loop (pre-scaled)
    int i = 0;
    for (; i + 8 <= len; i += 8) {
        // wave-uniform scalar indices -> s_load; keeps vmem pipe for g gathers
        int s0 = __builtin_amdgcn_readfirstlane(csr[start + i + 0]);
        int s1 = __builtin_amdgcn_readfirstlane(csr[start + i + 1]);
        int s2 = __builtin_amdgcn_readfirstlane(csr[start + i + 2]);
        int s3 = __builtin_amdgcn_readfirstlane(csr[start + i + 3]);
        int s4 = __builtin_amdgcn_readfirstlane(csr[start + i + 4]);
        int s5 = __builtin_amdgcn_readfirstlane(csr[start + i + 5]);
        int s6 = __builtin_amdgcn_readfirstlane(csr[start + i + 6]);
        int s7 = __builtin_amdgcn_readfirstlane(csr[start + i + 7]);
        u16 h0 = g[(unsigned)s0 * F + fc];
        u16 h1 = g[(unsigned)s1 * F + fc];
        u16 h2 = g[(unsigned)s2 * F + fc];
        u16 h3 = g[(unsigned)s3 * F + fc];
        u16 h4 = g[(unsigned)s4 * F + fc];
        u16 h5 = g[(unsigned)s5 * F + fc];
        u16 h6 = g[(unsigned)s6 * F + fc];
        u16 h7 = g[(unsigned)s7 * F + fc];
        acc += bf2f(h0) + bf2f(h1) + bf2f(h2) + bf2f(h3)
             + bf2f(h4) + bf2f(h5) + bf2f(h6) + bf2f(h7);
    }
    for (; i + 2 <= len; i += 2) {
        int s0 = __builtin_amdgcn_readfirstlane(csr[start + i + 0]);
        int s1 = __builtin_amdgcn_readfirstlane(csr[start + i + 1]);
        u16 h0 = g[(unsigned)s0 * F + fc];
        u16 h1 = g[(unsigned)s1 * F + fc];
        acc += bf2f(h0) + bf2f(h1);
    }
    if (i < len) {
        int s0 = __builtin_amdgcn_readfirstlane(csr[start + i]);
        acc += bf2f(g[(unsigned)s0 * F + fc]);
    }
    float v = dvn * acc + bf;
    if (!SOFTMAX) {
        if (f < (unsigned)F) out[(size_t)n * F + f] = v;
    } else {
        float vv = (f < (unsigned)F) ? v : -INFINITY;
        float m = vv;
#pragma unroll
        for (int off = 32; off; off >>= 1) m = fmaxf(m, __shfl_xor(m, off));
        float ex = (f < (unsigned)F) ? __expf(vv - m) : 0.f;
        float sum = ex;
#pragma unroll
        for (int off = 32; off; off >>= 1) sum += __shfl_xor(sum, off);
        if (f < (unsigned)F) out[(size_t)n * F + f] = vv - m - logf(sum);
    }
}

extern "C" void kernel_launch(void* const* d_in, const int* in_sizes, int n_in,
                              void* d_out, int out_size, void* d_ws, size_t ws_size,
                              hipStream_t stream) {
    const float* x  = (const float*)d_in[0];
    const void*  ei = d_in[1];
    const float* W1 = (const float*)d_in[2];
    const float* b1 = (const float*)d_in[3];
    const float* W2 = (const float*)d_in[4];
    const float* b2 = (const float*)d_in[5];
    const float* W3 = (const float*)d_in[6];
    const float* b3 = (const float*)d_in[7];
    float* out = (float*)d_out;

    char* ws = (char*)d_ws;
    size_t off = 0;
    auto alloc = [&](size_t bytes) { void* p = ws + off; off += (bytes + 255) & ~255ULL; return p; };
    int*   flag    = (int*)alloc(4);
    int*   counts  = (int*)alloc((size_t)EB * NB * 4);
    int*   pfx     = (int*)alloc((size_t)EB * NB * 4);
    int*   btot    = (int*)alloc(NB * 4);
    int*   bbase   = (int*)alloc((NB + 1) * 4);
    int*   deg     = (int*)alloc(NN * 4);
    float* dis     = (float*)alloc(NN * 4);
    int*   offs    = (int*)alloc(NN * 4);
    int*   csr_tmp = (int*)alloc((size_t)NE * 4);
    int*   csr     = (int*)alloc((size_t)NE * 4);
    u16*   gbuf    = (u16*)alloc((size_t)NN * 64 * 2);   // bf16 staging (12.8 MB)
    float* act     = (float*)alloc((size_t)NN * 64 * 4); // fp32 inter-layer activations

    // CSR build (deterministic two-phase counting sort; no global atomics)
    k_detect<<<1, 64, 0, stream>>>((const int*)ei, flag);
    k_hist<<<EB, 256, 0, stream>>>(ei, flag, counts);
    k_colscan<<<NB, 512, 0, stream>>>(counts, pfx, btot);
    k_bucketscan<<<1, 512, 0, stream>>>(btot, bbase);
    k_scatter<<<EB, 256, 0, stream>>>(ei, flag, pfx, bbase, csr_tmp);
    k_sort<<<NB, 256, 0, stream>>>(bbase, csr_tmp, csr, deg, offs, dis);

    const int gemm_grid = (NN + GB_NODES - 1) / GB_NODES;   // 391
    const int gather_grid = (NN + 3) / 4;

    // layer 1: g1 = bf16(dis*(x@W1)); out1 = dis*(sum g1) + b1  (ReLU fused into next gemm)
    k_gemm<128, 64, false><<<gemm_grid, 256, 0, stream>>>(x, W1, dis, gbuf);
    k_gather<64, false><<<gather_grid, 256, 0, stream>>>(offs, deg, csr, dis, gbuf, b1, act);

    // layer 2
    k_gemm<64, 64, true><<<gemm_grid, 256, 0, stream>>>(act, W2, dis, gbuf);
    k_gather<64, false><<<gather_grid, 256, 0, stream>>>(offs, deg, csr, dis, gbuf, b2, act);

    // layer 3 + fused log_softmax
    k_gemm<64, 40, true><<<gemm_grid, 256, 0, stream>>>(act, W3, dis, gbuf);
    k_gather<40, true><<<gather_grid, 256, 0, stream>>>(offs, deg, csr, dis, gbuf, b3, out);
}

// Round 7
// 347.037 us; speedup vs baseline: 4.2468x; 1.0376x over previous
//
#include <hip/hip_runtime.h>
#include <cstdint>
#include <cstddef>
#include <math.h>

#define NN 100000
#define NE 1600000
#define NB ((NN + 255) / 256)   // 391 node buckets (256 nodes each)
#define EB 400                  // phase-A edge blocks
#define EPB (NE / EB)           // 4000 edges per block

// GEMM tiling: 512 threads, 128 nodes/block, per-thread 4 nodes x 4 feats.
// grid = 782 blocks (~3 blocks/CU, ~24 waves/CU) -- the round-6 51us GEMM was
// occupancy-bound at 391 blocks x 4 waves (~12% occupancy).
#define GT_NODES 128
#define GT_KC 32
#define GT_STRIDE 132   // 128 + 4: keeps 16B alignment of xT rows (132*4 % 16 == 0)

typedef unsigned short u16;

__device__ __forceinline__ float bf2f(u16 u) {
    union { unsigned int i; float f; } c; c.i = ((unsigned int)u) << 16; return c.f;
}
__device__ __forceinline__ u16 f2bf(float f) {  // round-to-nearest-even
    union { float f; unsigned int i; } c; c.f = f;
    unsigned int lsb = (c.i >> 16) & 1u;
    return (u16)((c.i + 0x7fffu + lsb) >> 16);
}
__device__ __forceinline__ unsigned int pack2(float a, float b) {
    return (unsigned int)f2bf(a) | ((unsigned int)f2bf(b) << 16);
}

// ---------- index-width detection (int64 vs int32 edge_index) ----------
__global__ __launch_bounds__(64) void k_detect(const int* __restrict__ p, int* flag) {
    int nz = 0;
    for (int i = threadIdx.x; i < 1024; i += 64) nz |= (p[2 * i + 1] != 0);
    unsigned long long b = __ballot(nz != 0);
    if (threadIdx.x == 0) *flag = (b == 0ULL) ? 1 : 0;  // 1 => int64
}

__device__ __forceinline__ int load_idx(const void* ei, int isI64, int pos) {
    if (isI64) return (int)((const long long*)ei)[pos];
    return ((const int*)ei)[pos];
}

// ---------- phase A1: per-block bucket histogram ----------
__global__ __launch_bounds__(256) void k_hist(const void* __restrict__ ei,
                                              const int* __restrict__ flag,
                                              int* __restrict__ counts) {
    __shared__ int h[NB];
    for (int i = threadIdx.x; i < NB; i += 256) h[i] = 0;
    __syncthreads();
    int isI64 = *flag;
    int base = blockIdx.x * EPB;
    for (int i = threadIdx.x; i < EPB; i += 256) {
        int d = load_idx(ei, isI64, NE + base + i);
        atomicAdd(&h[d >> 8], 1);
    }
    __syncthreads();
    for (int i = threadIdx.x; i < NB; i += 256) counts[blockIdx.x * NB + i] = h[i];
}

// ---------- phase A2: column prefix over blocks (one block per bucket) ----------
__global__ __launch_bounds__(512) void k_colscan(const int* __restrict__ counts,
                                                 int* __restrict__ pfx,
                                                 int* __restrict__ btot) {
    __shared__ int t[512];
    int j = blockIdx.x;
    int v = (threadIdx.x < EB) ? counts[threadIdx.x * NB + j] : 0;
    t[threadIdx.x] = v;
    __syncthreads();
#pragma unroll
    for (int off = 1; off < 512; off <<= 1) {
        int u = (threadIdx.x >= off) ? t[threadIdx.x - off] : 0;
        __syncthreads();
        t[threadIdx.x] += u;
        __syncthreads();
    }
    if (threadIdx.x < EB) pfx[threadIdx.x * NB + j] = t[threadIdx.x] - v;  // exclusive
    if (threadIdx.x == 511) btot[j] = t[511];
}

// ---------- phase A3: exclusive scan of bucket totals ----------
__global__ __launch_bounds__(512) void k_bucketscan(const int* __restrict__ btot,
                                                    int* __restrict__ bbase) {
    __shared__ int t[512];
    int v = (threadIdx.x < NB) ? btot[threadIdx.x] : 0;
    t[threadIdx.x] = v;
    __syncthreads();
#pragma unroll
    for (int off = 1; off < 512; off <<= 1) {
        int u = (threadIdx.x >= off) ? t[threadIdx.x - off] : 0;
        __syncthreads();
        t[threadIdx.x] += u;
        __syncthreads();
    }
    if (threadIdx.x < NB) bbase[threadIdx.x] = t[threadIdx.x] - v;
    if (threadIdx.x == 511) bbase[NB] = t[511];  // == NE
}

// ---------- phase A4: scatter edges into bucket regions (no global atomics) ----------
// entry = (dstlocal << 17) | src   (src < 2^17, dstlocal < 256)
__global__ __launch_bounds__(256) void k_scatter(const void* __restrict__ ei,
                                                 const int* __restrict__ flag,
                                                 const int* __restrict__ pfx,
                                                 const int* __restrict__ bbase,
                                                 int* __restrict__ csr_tmp) {
    __shared__ int basel[NB];
    __shared__ int cur[NB];
    for (int i = threadIdx.x; i < NB; i += 256) {
        basel[i] = bbase[i] + pfx[blockIdx.x * NB + i];
        cur[i] = 0;
    }
    __syncthreads();
    int isI64 = *flag;
    int base = blockIdx.x * EPB;
    for (int i = threadIdx.x; i < EPB; i += 256) {
        int s = load_idx(ei, isI64, base + i);
        int d = load_idx(ei, isI64, NE + base + i);
        int bkt = d >> 8;
        int slot = basel[bkt] + atomicAdd(&cur[bkt], 1);
        csr_tmp[slot] = ((d & 255) << 17) | s;
    }
}

// ---------- phase B: per-bucket counting sort -> final csr + deg/offs/dis ----------
__global__ __launch_bounds__(256) void k_sort(const int* __restrict__ bbase,
                                              const int* __restrict__ csr_tmp,
                                              int* __restrict__ csr,
                                              int* __restrict__ deg,
                                              int* __restrict__ offs,
                                              float* __restrict__ dis) {
    __shared__ int h[256];
    __shared__ int sc[256];
    __shared__ int cur[256];
    int j = blockIdx.x;
    int s0 = bbase[j], s1 = bbase[j + 1];
    h[threadIdx.x] = 0;
    __syncthreads();
    for (int p = s0 + threadIdx.x; p < s1; p += 256)
        atomicAdd(&h[csr_tmp[p] >> 17], 1);
    __syncthreads();
    int v = h[threadIdx.x];
    sc[threadIdx.x] = v;
    __syncthreads();
#pragma unroll
    for (int off = 1; off < 256; off <<= 1) {
        int u = (threadIdx.x >= off) ? sc[threadIdx.x - off] : 0;
        __syncthreads();
        sc[threadIdx.x] += u;
        __syncthreads();
    }
    int excl = sc[threadIdx.x] - v;
    int node = j * 256 + threadIdx.x;
    if (node < NN) {
        deg[node] = v;
        offs[node] = s0 + excl;
        dis[node] = rsqrtf((float)(v + 1));  // +1 self-loop
    }
    cur[threadIdx.x] = excl;
    __syncthreads();
    for (int p = s0 + threadIdx.x; p < s1; p += 256) {
        int pk = csr_tmp[p];
        int dl = pk >> 17;
        int pos = s0 + atomicAdd(&cur[dl], 1);
        csr[pos] = pk & 0x1FFFF;
    }
}

// ---------- register-tiled GEMM (512 thr, 128 nodes/blk, 4x4/thread) ----------
// g[n][j] = bf16( dis[n] * (act(x)[n][:] @ W[:][j]) )
template <int K, int FR, bool RELU>
__global__ __launch_bounds__(512) void k_gemm(const float* __restrict__ x,
                                              const float* __restrict__ W,
                                              const float* __restrict__ dis,
                                              u16* __restrict__ out) {
    __shared__ float xT[GT_KC * GT_STRIDE];   // 16,896 B
    __shared__ float Wc[GT_KC * 64];          //  8,192 B
    const int tid = threadIdx.x;
    const int r = tid >> 4;    // 0..31 -> nodes r*4 .. r*4+3
    const int c = tid & 15;    // 0..15 -> feats c*4 .. c*4+3
    const int f4 = tid & 7;
    const int nrow = tid >> 3; // 0..63
    const int nbase = blockIdx.x * GT_NODES;

    float acc[4][4];
#pragma unroll
    for (int i = 0; i < 4; ++i)
#pragma unroll
        for (int j = 0; j < 4; ++j) acc[i][j] = 0.f;

    for (int kc = 0; kc < K; kc += GT_KC) {
        // stage W chunk: 32x64 floats (zero-pad feats >= FR)
#pragma unroll
        for (int q = 0; q < 4; ++q) {
            int e = q * 512 + tid;
            int kk = e >> 6, j = e & 63;
            Wc[kk * 64 + j] = (j < FR) ? W[(size_t)(kc + kk) * FR + j] : 0.f;
        }
        // stage x chunk transposed: 128 nodes x 32 k
#pragma unroll
        for (int q = 0; q < 2; ++q) {
            int nl = q * 64 + nrow;
            int n = nbase + nl;
            float4 v = make_float4(0.f, 0.f, 0.f, 0.f);
            if (n < NN) v = *(const float4*)(x + (size_t)n * K + kc + f4 * 4);
            if (RELU) {
                v.x = fmaxf(v.x, 0.f); v.y = fmaxf(v.y, 0.f);
                v.z = fmaxf(v.z, 0.f); v.w = fmaxf(v.w, 0.f);
            }
            xT[(f4 * 4 + 0) * GT_STRIDE + nl] = v.x;
            xT[(f4 * 4 + 1) * GT_STRIDE + nl] = v.y;
            xT[(f4 * 4 + 2) * GT_STRIDE + nl] = v.z;
            xT[(f4 * 4 + 3) * GT_STRIDE + nl] = v.w;
        }
        __syncthreads();
#pragma unroll 8
        for (int kk = 0; kk < GT_KC; ++kk) {
            float4 a = *(const float4*)&xT[kk * GT_STRIDE + r * 4];
            float4 w = *(const float4*)&Wc[kk * 64 + c * 4];
            float xa[4] = {a.x, a.y, a.z, a.w};
            float wb[4] = {w.x, w.y, w.z, w.w};
#pragma unroll
            for (int i = 0; i < 4; ++i)
#pragma unroll
                for (int j = 0; j < 4; ++j)
                    acc[i][j] = fmaf(xa[i], wb[j], acc[i][j]);
        }
        __syncthreads();
    }
    if (c * 4 < FR) {
#pragma unroll
        for (int i = 0; i < 4; ++i) {
            int n = nbase + r * 4 + i;
            if (n < NN) {
                float dv = dis[n];
                uint2 o;
                o.x = pack2(dv * acc[i][0], dv * acc[i][1]);
                o.y = pack2(dv * acc[i][2], dv * acc[i][3]);
                *(uint2*)(out + (size_t)n * FR + c * 4) = o;
            }
        }
    }
}

// ---------- gather aggregation (unweighted sum of pre-scaled bf16 g) ----------
// out[n][f] = dis[n] * ( g[n][f] + sum_e g[src_e][f] ) + b[f]
// csr indices forced wave-uniform scalar (s_load path); g addressed with
// 32-bit offsets from a uniform base (saddr global_load_ushort): ~3 VALU/edge.
template <int F, bool SOFTMAX>
__global__ __launch_bounds__(256) void k_gather(const int* __restrict__ offs,
                                                const int* __restrict__ deg,
                                                const int* __restrict__ csr,
                                                const float* __restrict__ dis,
                                                const u16* __restrict__ g,
                                                const float* __restrict__ b,
                                                float* __restrict__ out) {
    int n = blockIdx.x * 4 + (threadIdx.x >> 6);
    unsigned f = threadIdx.x & 63;
    if (n >= NN) return;
    unsigned fc = (f < (unsigned)F) ? f : 0u;
    int start = __builtin_amdgcn_readfirstlane(offs[n]);
    int len   = __builtin_amdgcn_readfirstlane(deg[n]);
    float dvn = dis[n];
    float bf  = b[fc];
    float acc = bf2f(g[(unsigned)n * F + fc]);  // self-loop (pre-scaled)
    int i = 0;
    for (; i + 8 <= len; i += 8) {
        int s0 = __builtin_amdgcn_readfirstlane(csr[start + i + 0]);
        int s1 = __builtin_amdgcn_readfirstlane(csr[start + i + 1]);
        int s2 = __builtin_amdgcn_readfirstlane(csr[start + i + 2]);
        int s3 = __builtin_amdgcn_readfirstlane(csr[start + i + 3]);
        int s4 = __builtin_amdgcn_readfirstlane(csr[start + i + 4]);
        int s5 = __builtin_amdgcn_readfirstlane(csr[start + i + 5]);
        int s6 = __builtin_amdgcn_readfirstlane(csr[start + i + 6]);
        int s7 = __builtin_amdgcn_readfirstlane(csr[start + i + 7]);
        u16 h0 = g[(unsigned)s0 * F + fc];
        u16 h1 = g[(unsigned)s1 * F + fc];
        u16 h2 = g[(unsigned)s2 * F + fc];
        u16 h3 = g[(unsigned)s3 * F + fc];
        u16 h4 = g[(unsigned)s4 * F + fc];
        u16 h5 = g[(unsigned)s5 * F + fc];
        u16 h6 = g[(unsigned)s6 * F + fc];
        u16 h7 = g[(unsigned)s7 * F + fc];
        acc += bf2f(h0) + bf2f(h1) + bf2f(h2) + bf2f(h3)
             + bf2f(h4) + bf2f(h5) + bf2f(h6) + bf2f(h7);
    }
    for (; i + 2 <= len; i += 2) {
        int s0 = __builtin_amdgcn_readfirstlane(csr[start + i + 0]);
        int s1 = __builtin_amdgcn_readfirstlane(csr[start + i + 1]);
        u16 h0 = g[(unsigned)s0 * F + fc];
        u16 h1 = g[(unsigned)s1 * F + fc];
        acc += bf2f(h0) + bf2f(h1);
    }
    if (i < len) {
        int s0 = __builtin_amdgcn_readfirstlane(csr[start + i]);
        acc += bf2f(g[(unsigned)s0 * F + fc]);
    }
    float v = dvn * acc + bf;
    if (!SOFTMAX) {
        if (f < (unsigned)F) out[(size_t)n * F + f] = v;
    } else {
        float vv = (f < (unsigned)F) ? v : -INFINITY;
        float m = vv;
#pragma unroll
        for (int off = 32; off; off >>= 1) m = fmaxf(m, __shfl_xor(m, off));
        float ex = (f < (unsigned)F) ? __expf(vv - m) : 0.f;
        float sum = ex;
#pragma unroll
        for (int off = 32; off; off >>= 1) sum += __shfl_xor(sum, off);
        if (f < (unsigned)F) out[(size_t)n * F + f] = vv - m - logf(sum);
    }
}

extern "C" void kernel_launch(void* const* d_in, const int* in_sizes, int n_in,
                              void* d_out, int out_size, void* d_ws, size_t ws_size,
                              hipStream_t stream) {
    const float* x  = (const float*)d_in[0];
    const void*  ei = d_in[1];
    const float* W1 = (const float*)d_in[2];
    const float* b1 = (const float*)d_in[3];
    const float* W2 = (const float*)d_in[4];
    const float* b2 = (const float*)d_in[5];
    const float* W3 = (const float*)d_in[6];
    const float* b3 = (const float*)d_in[7];
    float* out = (float*)d_out;

    char* ws = (char*)d_ws;
    size_t off = 0;
    auto alloc = [&](size_t bytes) { void* p = ws + off; off += (bytes + 255) & ~255ULL; return p; };
    int*   flag    = (int*)alloc(4);
    int*   counts  = (int*)alloc((size_t)EB * NB * 4);
    int*   pfx     = (int*)alloc((size_t)EB * NB * 4);
    int*   btot    = (int*)alloc(NB * 4);
    int*   bbase   = (int*)alloc((NB + 1) * 4);
    int*   deg     = (int*)alloc(NN * 4);
    float* dis     = (float*)alloc(NN * 4);
    int*   offs    = (int*)alloc(NN * 4);
    int*   csr_tmp = (int*)alloc((size_t)NE * 4);
    int*   csr     = (int*)alloc((size_t)NE * 4);
    u16*   gbuf    = (u16*)alloc((size_t)NN * 64 * 2);   // bf16 staging (12.8 MB)
    float* act     = (float*)alloc((size_t)NN * 64 * 4); // fp32 inter-layer activations

    // CSR build (deterministic two-phase counting sort; no global atomics)
    k_detect<<<1, 64, 0, stream>>>((const int*)ei, flag);
    k_hist<<<EB, 256, 0, stream>>>(ei, flag, counts);
    k_colscan<<<NB, 512, 0, stream>>>(counts, pfx, btot);
    k_bucketscan<<<1, 512, 0, stream>>>(btot, bbase);
    k_scatter<<<EB, 256, 0, stream>>>(ei, flag, pfx, bbase, csr_tmp);
    k_sort<<<NB, 256, 0, stream>>>(bbase, csr_tmp, csr, deg, offs, dis);

    const int gemm_grid = (NN + GT_NODES - 1) / GT_NODES;   // 782
    const int gather_grid = (NN + 3) / 4;

    // layer 1: g1 = bf16(dis*(x@W1)); out1 = dis*(sum g1) + b1  (ReLU fused into next gemm)
    k_gemm<128, 64, false><<<gemm_grid, 512, 0, stream>>>(x, W1, dis, gbuf);
    k_gather<64, false><<<gather_grid, 256, 0, stream>>>(offs, deg, csr, dis, gbuf, b1, act);

    // layer 2
    k_gemm<64, 64, true><<<gemm_grid, 512, 0, stream>>>(act, W2, dis, gbuf);
    k_gather<64, false><<<gather_grid, 256, 0, stream>>>(offs, deg, csr, dis, gbuf, b2, act);

    // layer 3 + fused log_softmax
    k_gemm<64, 40, true><<<gemm_grid, 512, 0, stream>>>(act, W3, dis, gbuf);
    k_gather<40, true><<<gather_grid, 256, 0, stream>>>(offs, deg, csr, dis, gbuf, b3, out);
}